// Round 1
// baseline (1329.166 us; speedup 1.0000x reference)
//
#include <hip/hip_runtime.h>
#include <hip/hip_bf16.h>

#define TPB 256

// ---------------------------------------------------------------------------
// Kernel 1: eigen-filtered Koopman graphs. 32 matrices of 8x8.
// One block of 256 threads; 8 lanes per matrix (lane r owns root r).
// ---------------------------------------------------------------------------
__global__ __launch_bounds__(256) void eig_filter_kernel(
    const float* __restrict__ Kt, float* __restrict__ Gout)
{
  const int tid = threadIdx.x;
  const int g = tid >> 3;        // matrix index 0..31
  const int r = tid & 7;         // root index 0..7
  const int lanebase = tid & 56; // within-wave 8-lane group base

  __shared__ double Kd[32][64];
  __shared__ double Pw[32][64];
  __shared__ double psum[32][8];
  __shared__ double coef[32][9];

  #pragma unroll
  for (int e = 0; e < 8; ++e) {
    double v = (double)Kt[g * 64 + r * 8 + e];
    Kd[g][r * 8 + e] = v;
    Pw[g][r * 8 + e] = v;
  }
  __syncthreads();

  // Power sums p_k = tr(K^k), k=1..8 (cooperative: lane r computes row r)
  for (int p = 1; p <= 8; ++p) {
    if (r == 0) {
      double tr = 0.0;
      for (int d = 0; d < 8; ++d) tr += Pw[g][d * 8 + d];
      psum[g][p - 1] = tr;
    }
    __syncthreads();
    if (p < 8) {
      double nr[8];
      for (int c = 0; c < 8; ++c) {
        double s = 0.0;
        for (int k = 0; k < 8; ++k) s += Pw[g][r * 8 + k] * Kd[g][k * 8 + c];
        nr[c] = s;
      }
      __syncthreads();
      for (int c = 0; c < 8; ++c) Pw[g][r * 8 + c] = nr[c];
      __syncthreads();
    }
  }

  // Newton's identities -> monic char poly lambda^8 + a1 l^7 + ... + a8
  if (r == 0) {
    double a[9];
    a[0] = 1.0;
    for (int k = 1; k <= 8; ++k) {
      double s = psum[g][k - 1];
      for (int i = 1; i < k; ++i) s += a[i] * psum[g][k - i - 1];
      a[k] = -s / (double)k;
    }
    for (int k = 0; k <= 8; ++k) coef[g][k] = a[k];
  }
  __syncthreads();

  double a8[9];
  #pragma unroll
  for (int k = 0; k <= 8; ++k) a8[k] = coef[g][k];

  // Durand-Kerner: lane r iterates root r; exchange via wave shuffles.
  double zre = 1.0, zim = 0.0;
  for (int q = 0; q <= r; ++q) {  // (0.4+0.9i)^(r+1)
    double t1 = zre * 0.4 - zim * 0.9;
    double t2 = zre * 0.9 + zim * 0.4;
    zre = t1; zim = t2;
  }
  for (int it = 0; it < 120; ++it) {
    double pre = a8[0], pim = 0.0;
    #pragma unroll
    for (int k = 1; k <= 8; ++k) {
      double t1 = pre * zre - pim * zim + a8[k];
      double t2 = pre * zim + pim * zre;
      pre = t1; pim = t2;
    }
    double dre = 1.0, dim = 0.0;
    for (int j = 0; j < 8; ++j) {
      double ore = __shfl(zre, lanebase + j, 64);
      double oim = __shfl(zim, lanebase + j, 64);
      if (j != r) {
        double sre = zre - ore, sim = zim - oim;
        double t1 = dre * sre - dim * sim;
        double t2 = dre * sim + dim * sre;
        dre = t1; dim = t2;
      }
    }
    double d2 = dre * dre + dim * dim;
    if (d2 < 1e-60) d2 = 1e-60;
    double qre = (pre * dre + pim * dim) / d2;
    double qim = (pim * dre - pre * dim) / d2;
    zre -= qre; zim -= qim;
  }

  // all roots of this matrix
  double lre[8], lim[8];
  #pragma unroll
  for (int j = 0; j < 8; ++j) {
    lre[j] = __shfl(zre, lanebase + j, 64);
    lim[j] = __shfl(zim, lanebase + j, 64);
  }

  // mask: |lambda + (1e-10 + 1e-10 i)| in [0.9, 1.1]; fallback: keep all
  double sre = zre + 1e-10, sim = zim + 1e-10;
  double amod = sqrt(sre * sre + sim * sim);
  bool m = (amod <= 1.1) && (amod >= 0.9);
  unsigned long long bal = __ballot(m);
  if (((bal >> lanebase) & 0xFFull) == 0ull) m = true;

  // Lagrange basis numerator: M = prod_{j != r} (K - l_j I)   (complex fp64)
  double Mre[64], Mim[64];
  {
    int first = (r == 0) ? 1 : 0;
    for (int e = 0; e < 64; ++e) { Mre[e] = Kd[g][e]; Mim[e] = 0.0; }
    for (int d = 0; d < 8; ++d) { Mre[d * 9] -= lre[first]; Mim[d * 9] -= lim[first]; }
    for (int j = 0; j < 8; ++j) {
      if (j == r || j == first) continue;
      double Tre[64], Tim[64];
      for (int rr = 0; rr < 8; ++rr) {
        for (int cc = 0; cc < 8; ++cc) {
          double accre = 0.0, accim = 0.0;
          for (int k = 0; k < 8; ++k) {
            double bre = Kd[g][k * 8 + cc] - ((k == cc) ? lre[j] : 0.0);
            double bim = (k == cc) ? -lim[j] : 0.0;
            double mre = Mre[rr * 8 + k], mim = Mim[rr * 8 + k];
            accre += mre * bre - mim * bim;
            accim += mre * bim + mim * bre;
          }
          Tre[rr * 8 + cc] = accre; Tim[rr * 8 + cc] = accim;
        }
      }
      for (int e = 0; e < 64; ++e) { Mre[e] = Tre[e]; Mim[e] = Tim[e]; }
    }
  }

  // c_r = f(lambda_r) / prod_{j != r}(lambda_r - lambda_j), f(l) = (l+eps)*m
  double dre = 1.0, dim = 0.0;
  for (int j = 0; j < 8; ++j) {
    if (j == r) continue;
    double ure = zre - lre[j], uim = zim - lim[j];
    double t1 = dre * ure - dim * uim;
    double t2 = dre * uim + dim * ure;
    dre = t1; dim = t2;
  }
  double numre = m ? (zre + 1e-10) : 0.0;
  double numim = m ? (zim + 1e-10) : 0.0;
  double dd = dre * dre + dim * dim;
  if (dd < 1e-300) dd = 1e-300;
  double cre = (numre * dre + numim * dim) / dd;
  double cim = (numim * dre - numre * dim) / dd;

  // G = sum_r Re(c_r * M_r), reduced across the 8-lane group
  for (int e = 0; e < 64; ++e) {
    double v = cre * Mre[e] - cim * Mim[e];
    v += __shfl_xor(v, 1, 64);
    v += __shfl_xor(v, 2, 64);
    v += __shfl_xor(v, 4, 64);
    if (r == 0) Gout[g * 64 + e] = (float)v;
  }
}

// ---------------------------------------------------------------------------
// Kernel 2: community argmax -> class per node
// ---------------------------------------------------------------------------
__global__ __launch_bounds__(256) void argmax_kernel(
    const float* __restrict__ comm, int* __restrict__ cls, int N)
{
  int n = blockIdx.x * 256 + threadIdx.x;
  if (n >= N) return;
  const float* row = comm + n * 32;
  float best = row[0];
  int bi = 0;
  #pragma unroll
  for (int c = 1; c < 32; ++c) {
    float v = row[c];
    if (v > best) { best = v; bi = c; }
  }
  cls[n] = bi;
}

// ---------------------------------------------------------------------------
// Kernel 3: parent matmul + 3 coupling blocks + logprob. Thread-per-sample.
// Weights read at wave-uniform addresses -> compiler scalarizes to s_load.
// Hidden vector bounced through LDS (lane-own-column) to keep register
// arrays statically indexed.
// ---------------------------------------------------------------------------
__global__ __launch_bounds__(256) void causal_main_kernel(
    const float* __restrict__ latent, const float* __restrict__ graphs,
    const int* __restrict__ cls,
    const float* __restrict__ W0, const float* __restrict__ b0,
    const float* __restrict__ W1, const float* __restrict__ b1,
    const float* __restrict__ W2, const float* __restrict__ b2,
    float* __restrict__ out)
{
  __shared__ float h64[64][TPB];
  const int tid = threadIdx.x;
  const int s = blockIdx.x * TPB + tid;   // sample id, < 2^21
  const int n = (s >> 4) & 4095;          // node id (T=16, N=4096)

  float x[8];
  {
    const float4 xa = *(const float4*)(latent + (size_t)s * 8);
    const float4 xb = *(const float4*)(latent + (size_t)s * 8 + 4);
    x[0] = xa.x; x[1] = xa.y; x[2] = xa.z; x[3] = xa.w;
    x[4] = xb.x; x[5] = xb.y; x[6] = xb.z; x[7] = xb.w;
  }

  // parent = x @ G[cls[n]]
  float par[8];
  {
    const float* G = graphs + cls[n] * 64;
    #pragma unroll
    for (int e = 0; e < 8; ++e) par[e] = 0.f;
    #pragma unroll
    for (int d = 0; d < 8; ++d) {
      const float xd = x[d];
      const float4 g0 = *(const float4*)(G + d * 8);
      const float4 g1 = *(const float4*)(G + d * 8 + 4);
      par[0] += xd * g0.x; par[1] += xd * g0.y; par[2] += xd * g0.z; par[3] += xd * g0.w;
      par[4] += xd * g1.x; par[5] += xd * g1.y; par[6] += xd * g1.z; par[7] += xd * g1.w;
    }
  }

  float logdet = 0.f;

  #pragma unroll
  for (int i = 0; i < 3; ++i) {
    const int in0 = (i & 1) ? 4 : 0;  // MLP input half
    const int tr0 = (i & 1) ? 0 : 4;  // transformed half

    float h0[12];
    #pragma unroll
    for (int q = 0; q < 4; ++q) h0[q] = x[in0 + q];
    #pragma unroll
    for (int q = 0; q < 8; ++q) h0[4 + q] = par[q];

    // layer 1: 12 -> 64
    float acc[64];
    #pragma unroll
    for (int j = 0; j < 64; ++j) acc[j] = b0[i * 64 + j];
    #pragma unroll
    for (int k = 0; k < 12; ++k) {
      const float v = h0[k];
      const float* wr = W0 + (i * 12 + k) * 64;
      #pragma unroll
      for (int j = 0; j < 64; ++j) acc[j] += v * wr[j];
    }
    #pragma unroll
    for (int j = 0; j < 64; ++j) h64[j][tid] = fmaxf(acc[j], 0.f);

    // layer 2: 64 -> 64
    float acc2[64];
    #pragma unroll
    for (int j = 0; j < 64; ++j) acc2[j] = b1[i * 64 + j];
    for (int k = 0; k < 64; ++k) {          // rolled: uniform weight rows
      const float v = h64[k][tid];
      const float* wr = W1 + (i * 64 + k) * 64;
      #pragma unroll
      for (int j = 0; j < 64; ++j) acc2[j] += v * wr[j];
    }
    #pragma unroll
    for (int j = 0; j < 64; ++j) h64[j][tid] = fmaxf(acc2[j], 0.f);

    // layer 3: 64 -> 8
    float o[8];
    #pragma unroll
    for (int j = 0; j < 8; ++j) o[j] = b2[i * 8 + j];
    for (int k = 0; k < 64; ++k) {          // rolled
      const float v = h64[k][tid];
      const float* wr = W2 + (i * 64 + k) * 8;
      #pragma unroll
      for (int j = 0; j < 8; ++j) o[j] += v * wr[j];
    }

    // affine transform of the other half
    #pragma unroll
    for (int q = 0; q < 4; ++q) {
      const float sv = tanhf(o[q]);
      const float tv = o[4 + q];
      x[tr0 + q] = x[tr0 + q] * expf(sv) + tv;
      logdet += sv;
    }
  }

  float ss = 0.f;
  #pragma unroll
  for (int q = 0; q < 8; ++q) ss += x[q] * x[q];
  // c = 0.5 * 8 * ln(2*pi)
  out[s] = -0.5f * ss - 7.3515082656373810f + logdet;
}

// ---------------------------------------------------------------------------
extern "C" void kernel_launch(void* const* d_in, const int* in_sizes, int n_in,
                              void* d_out, int out_size, void* d_ws, size_t ws_size,
                              hipStream_t stream) {
  const float* latent  = (const float*)d_in[0];
  const float* koopman = (const float*)d_in[1];
  const float* comm    = (const float*)d_in[2];
  const float* W0      = (const float*)d_in[3];
  const float* b0      = (const float*)d_in[4];
  const float* W1      = (const float*)d_in[5];
  const float* b1      = (const float*)d_in[6];
  const float* W2      = (const float*)d_in[7];
  const float* b2      = (const float*)d_in[8];
  float* out = (float*)d_out;

  float* graphs_ws = (float*)d_ws;                       // 32*64 floats
  int*   cls_ws    = (int*)((char*)d_ws + 32 * 64 * 4);  // 4096 ints

  eig_filter_kernel<<<1, 256, 0, stream>>>(koopman, graphs_ws);
  argmax_kernel<<<16, 256, 0, stream>>>(comm, cls_ws, 4096);

  const int total = 32 * 4096 * 16;  // 2,097,152 samples
  causal_main_kernel<<<total / TPB, TPB, 0, stream>>>(
      latent, graphs_ws, cls_ws, W0, b0, W1, b1, W2, b2, out);
}

// Round 2
// 915.185 us; speedup vs baseline: 1.4523x; 1.4523x over previous
//
#include <hip/hip_runtime.h>
#include <hip/hip_bf16.h>

typedef __attribute__((ext_vector_type(8))) short     bf16x8;
typedef __attribute__((ext_vector_type(4))) float     f32x4;
typedef __attribute__((ext_vector_type(4))) unsigned  u32x4;

// ---------------------------------------------------------------------------
// helpers: round-to-nearest bf16 + hi/lo split (x ~= hi + lo, ~17 mantissa bits)
// ---------------------------------------------------------------------------
__device__ inline unsigned short bf16_rn(float x) {
  unsigned u = __float_as_uint(x);
  unsigned r = (u + 0x7FFFu + ((u >> 16) & 1u)) >> 16;
  return (unsigned short)r;
}
__device__ inline void split_bf16(float x, unsigned short& h, unsigned short& l) {
  h = bf16_rn(x);
  float hf = __uint_as_float(((unsigned)h) << 16);
  l = bf16_rn(x - hf);
}

// ---------------------------------------------------------------------------
// Kernel 1: eigen-filtered Koopman graphs (unchanged from round 1 — passed)
// ---------------------------------------------------------------------------
__global__ __launch_bounds__(256) void eig_filter_kernel(
    const float* __restrict__ Kt, float* __restrict__ Gout)
{
  const int tid = threadIdx.x;
  const int g = tid >> 3;
  const int r = tid & 7;
  const int lanebase = tid & 56;

  __shared__ double Kd[32][64];
  __shared__ double Pw[32][64];
  __shared__ double psum[32][8];
  __shared__ double coef[32][9];

  #pragma unroll
  for (int e = 0; e < 8; ++e) {
    double v = (double)Kt[g * 64 + r * 8 + e];
    Kd[g][r * 8 + e] = v;
    Pw[g][r * 8 + e] = v;
  }
  __syncthreads();

  for (int p = 1; p <= 8; ++p) {
    if (r == 0) {
      double tr = 0.0;
      for (int d = 0; d < 8; ++d) tr += Pw[g][d * 8 + d];
      psum[g][p - 1] = tr;
    }
    __syncthreads();
    if (p < 8) {
      double nr[8];
      for (int c = 0; c < 8; ++c) {
        double s = 0.0;
        for (int k = 0; k < 8; ++k) s += Pw[g][r * 8 + k] * Kd[g][k * 8 + c];
        nr[c] = s;
      }
      __syncthreads();
      for (int c = 0; c < 8; ++c) Pw[g][r * 8 + c] = nr[c];
      __syncthreads();
    }
  }

  if (r == 0) {
    double a[9];
    a[0] = 1.0;
    for (int k = 1; k <= 8; ++k) {
      double ssum = psum[g][k - 1];
      for (int i = 1; i < k; ++i) ssum += a[i] * psum[g][k - i - 1];
      a[k] = -ssum / (double)k;
    }
    for (int k = 0; k <= 8; ++k) coef[g][k] = a[k];
  }
  __syncthreads();

  double a8[9];
  #pragma unroll
  for (int k = 0; k <= 8; ++k) a8[k] = coef[g][k];

  double zre = 1.0, zim = 0.0;
  for (int q = 0; q <= r; ++q) {
    double t1 = zre * 0.4 - zim * 0.9;
    double t2 = zre * 0.9 + zim * 0.4;
    zre = t1; zim = t2;
  }
  for (int it = 0; it < 120; ++it) {
    double pre = a8[0], pim = 0.0;
    #pragma unroll
    for (int k = 1; k <= 8; ++k) {
      double t1 = pre * zre - pim * zim + a8[k];
      double t2 = pre * zim + pim * zre;
      pre = t1; pim = t2;
    }
    double dre = 1.0, dim = 0.0;
    for (int j = 0; j < 8; ++j) {
      double ore = __shfl(zre, lanebase + j, 64);
      double oim = __shfl(zim, lanebase + j, 64);
      if (j != r) {
        double sre = zre - ore, sim = zim - oim;
        double t1 = dre * sre - dim * sim;
        double t2 = dre * sim + dim * sre;
        dre = t1; dim = t2;
      }
    }
    double d2 = dre * dre + dim * dim;
    if (d2 < 1e-60) d2 = 1e-60;
    double qre = (pre * dre + pim * dim) / d2;
    double qim = (pim * dre - pre * dim) / d2;
    zre -= qre; zim -= qim;
  }

  double lre[8], lim[8];
  #pragma unroll
  for (int j = 0; j < 8; ++j) {
    lre[j] = __shfl(zre, lanebase + j, 64);
    lim[j] = __shfl(zim, lanebase + j, 64);
  }

  double sre = zre + 1e-10, sim = zim + 1e-10;
  double amod = sqrt(sre * sre + sim * sim);
  bool m = (amod <= 1.1) && (amod >= 0.9);
  unsigned long long bal = __ballot(m);
  if (((bal >> lanebase) & 0xFFull) == 0ull) m = true;

  double Mre[64], Mim[64];
  {
    int first = (r == 0) ? 1 : 0;
    for (int e = 0; e < 64; ++e) { Mre[e] = Kd[g][e]; Mim[e] = 0.0; }
    for (int d = 0; d < 8; ++d) { Mre[d * 9] -= lre[first]; Mim[d * 9] -= lim[first]; }
    for (int j = 0; j < 8; ++j) {
      if (j == r || j == first) continue;
      double Tre[64], Tim[64];
      for (int rr = 0; rr < 8; ++rr) {
        for (int cc = 0; cc < 8; ++cc) {
          double accre = 0.0, accim = 0.0;
          for (int k = 0; k < 8; ++k) {
            double bre = Kd[g][k * 8 + cc] - ((k == cc) ? lre[j] : 0.0);
            double bim = (k == cc) ? -lim[j] : 0.0;
            double mre = Mre[rr * 8 + k], mim = Mim[rr * 8 + k];
            accre += mre * bre - mim * bim;
            accim += mre * bim + mim * bre;
          }
          Tre[rr * 8 + cc] = accre; Tim[rr * 8 + cc] = accim;
        }
      }
      for (int e = 0; e < 64; ++e) { Mre[e] = Tre[e]; Mim[e] = Tim[e]; }
    }
  }

  double dre = 1.0, dim = 0.0;
  for (int j = 0; j < 8; ++j) {
    if (j == r) continue;
    double ure = zre - lre[j], uim = zim - lim[j];
    double t1 = dre * ure - dim * uim;
    double t2 = dre * uim + dim * ure;
    dre = t1; dim = t2;
  }
  double numre = m ? (zre + 1e-10) : 0.0;
  double numim = m ? (zim + 1e-10) : 0.0;
  double dd = dre * dre + dim * dim;
  if (dd < 1e-300) dd = 1e-300;
  double cre = (numre * dre + numim * dim) / dd;
  double cim = (numim * dre - numre * dim) / dd;

  for (int e = 0; e < 64; ++e) {
    double v = cre * Mre[e] - cim * Mim[e];
    v += __shfl_xor(v, 1, 64);
    v += __shfl_xor(v, 2, 64);
    v += __shfl_xor(v, 4, 64);
    if (r == 0) Gout[g * 64 + e] = (float)v;
  }
}

// ---------------------------------------------------------------------------
// Kernel 2: community argmax
// ---------------------------------------------------------------------------
__global__ __launch_bounds__(256) void argmax_kernel(
    const float* __restrict__ comm, int* __restrict__ cls, int N)
{
  int n = blockIdx.x * 256 + threadIdx.x;
  if (n >= N) return;
  const float* row = comm + n * 32;
  float best = row[0];
  int bi = 0;
  #pragma unroll
  for (int c = 1; c < 32; ++c) {
    float v = row[c];
    if (v > best) { best = v; bi = c; }
  }
  cls[n] = bi;
}

// ---------------------------------------------------------------------------
// Kernel 3: pre-pack weights into MFMA B-fragment layout (hi/lo bf16 planes).
// B[32k x 16n] frag: lane (c=l&15, g=l>>4) holds B[8g+j][c], j=0..7, as 4 dwords.
// Frag table per coupling block i (28 frags):
//   0..7  : L0 (W0, K pad 12->32): ni*2 + plane
//   8..23 : L1 (W1 64x64):         ki*8 + ni*2 + plane
//   24..27: L2 (W2 64x8, N pad 16): ki*2 + plane
// Each frag = 64 lanes * 16B = 1KB in ws.
// ---------------------------------------------------------------------------
__global__ __launch_bounds__(256) void wpack_kernel(
    const float* __restrict__ W0, const float* __restrict__ W1,
    const float* __restrict__ W2, unsigned* __restrict__ wfrag)
{
  int gid = blockIdx.x * 256 + threadIdx.x;
  if (gid >= 84 * 64) return;
  int fid = gid >> 6, lane = gid & 63;
  int i = fid / 28, fl = fid % 28;
  int c = lane & 15, g = lane >> 4;
  int ki, ni, plane, layer;
  if (fl < 8)       { layer = 0; ki = 0;          ni = fl >> 1;       plane = fl & 1; }
  else if (fl < 24) { layer = 1; int q = fl - 8;  ki = q >> 3; ni = (q >> 1) & 3; plane = q & 1; }
  else              { layer = 2; int q = fl - 24; ki = q >> 1; ni = 0; plane = q & 1; }

  unsigned short vals[8];
  #pragma unroll
  for (int j = 0; j < 8; ++j) {
    int k = ki * 32 + g * 8 + j;
    int n = ni * 16 + c;
    float v = 0.f;
    if (layer == 0)      { if (k < 12) v = W0[i * 12 * 64 + k * 64 + n]; }
    else if (layer == 1) { v = W1[i * 64 * 64 + k * 64 + n]; }
    else                 { if (n < 8)  v = W2[i * 64 * 8 + k * 8 + n]; }
    unsigned short h, l;
    split_bf16(v, h, l);
    vals[j] = plane ? l : h;
  }
  u32x4 o;
  #pragma unroll
  for (int tt = 0; tt < 4; ++tt)
    o[tt] = (unsigned)vals[2 * tt] | ((unsigned)vals[2 * tt + 1] << 16);
  *(u32x4*)(wfrag + fid * 256 + lane * 4) = o;
}

// ---------------------------------------------------------------------------
// Kernel 4: main — MFMA coupling chain. 128 samples/block, 2 waves.
// Wave w: samples 64w..64w+63 (4 m-frags), all 64 features (4 n-frags).
// Split-bf16: acc = bias + Ah*Wh + Ah*Wl + Al*Wh  (f32 accumulate).
// H planes [128][64] bf16 in LDS with XOR block swizzle (blk ^= s&7).
// ---------------------------------------------------------------------------
#define SPB 128

__global__ __launch_bounds__(128) void causal_mfma_kernel(
    const float* __restrict__ latent, const float* __restrict__ graphs,
    const int* __restrict__ cls, const unsigned* __restrict__ wfrag,
    const float* __restrict__ b0, const float* __restrict__ b1,
    const float* __restrict__ b2, float* __restrict__ out)
{
  __shared__ char Hsh[2][16384];   // activation planes (hi, lo)
  __shared__ char UO[10240];       // U: 2 planes x [128][16]bf16 ; O: [128][20] f32

  const int t    = threadIdx.x;
  const int lane = t & 63;
  const int c    = lane & 15;
  const int g    = lane >> 4;
  const int w    = t >> 6;
  const int s    = blockIdx.x * SPB + t;

  // ---- per-thread sample state
  float x[8];
  {
    const float4 xa = *(const float4*)(latent + (size_t)s * 8);
    const float4 xb = *(const float4*)(latent + (size_t)s * 8 + 4);
    x[0] = xa.x; x[1] = xa.y; x[2] = xa.z; x[3] = xa.w;
    x[4] = xb.x; x[5] = xb.y; x[6] = xb.z; x[7] = xb.w;
  }
  float par[8];
  {
    const int n = (s >> 4) & 4095;
    const float* G = graphs + cls[n] * 64;
    #pragma unroll
    for (int e = 0; e < 8; ++e) par[e] = 0.f;
    #pragma unroll
    for (int d = 0; d < 8; ++d) {
      const float xd = x[d];
      const float4 g0 = *(const float4*)(G + d * 8);
      const float4 g1 = *(const float4*)(G + d * 8 + 4);
      par[0] += xd * g0.x; par[1] += xd * g0.y; par[2] += xd * g0.z; par[3] += xd * g0.w;
      par[4] += xd * g1.x; par[5] += xd * g1.y; par[6] += xd * g1.z; par[7] += xd * g1.w;
    }
  }
  float logdet = 0.f;

  for (int i = 0; i < 3; ++i) {
    const int in0 = (i & 1) ? 4 : 0;
    const int tr0 = (i & 1) ? 0 : 4;

    // ---- U phase: thread t writes row t of U planes ([128][16] bf16 each)
    {
      float u[12];
      #pragma unroll
      for (int q = 0; q < 4; ++q) u[q] = x[in0 + q];
      #pragma unroll
      for (int q = 0; q < 8; ++q) u[4 + q] = par[q];
      u32x4 hiA, hiB, loA, loB;
      #pragma unroll
      for (int q = 0; q < 6; ++q) {
        unsigned short h0, l0, h1, l1;
        split_bf16(u[2 * q], h0, l0);
        split_bf16(u[2 * q + 1], h1, l1);
        unsigned hd = (unsigned)h0 | ((unsigned)h1 << 16);
        unsigned ld = (unsigned)l0 | ((unsigned)l1 << 16);
        if (q < 4) { hiA[q] = hd; loA[q] = ld; }
        else       { hiB[q - 4] = hd; loB[q - 4] = ld; }
      }
      hiB[2] = 0; hiB[3] = 0; loB[2] = 0; loB[3] = 0;
      *(u32x4*)(UO + t * 32)            = hiA;
      *(u32x4*)(UO + t * 32 + 16)       = hiB;
      *(u32x4*)(UO + 4096 + t * 32)     = loA;
      *(u32x4*)(UO + 4096 + t * 32 + 16)= loB;
    }
    __syncthreads();

    f32x4 acc[4][4];

    // ---- L1: [128x32(pad)] @ [32x64]
    {
      #pragma unroll
      for (int ni = 0; ni < 4; ++ni) {
        float bv = b0[i * 64 + ni * 16 + c];
        #pragma unroll
        for (int mi = 0; mi < 4; ++mi) acc[mi][ni] = f32x4{bv, bv, bv, bv};
      }
      bf16x8 ah[4], al[4];
      const bf16x8 zz = {0, 0, 0, 0, 0, 0, 0, 0};
      #pragma unroll
      for (int mi = 0; mi < 4; ++mi) {
        int sl = w * 64 + mi * 16 + c;
        ah[mi] = (g < 2) ? *(const bf16x8*)(UO + sl * 32 + g * 16) : zz;
        al[mi] = (g < 2) ? *(const bf16x8*)(UO + 4096 + sl * 32 + g * 16) : zz;
      }
      bf16x8 wh[4], wl[4];
      #pragma unroll
      for (int ni = 0; ni < 4; ++ni) {
        wh[ni] = *(const bf16x8*)((const char*)wfrag + (size_t)(i * 28 + ni * 2 + 0) * 1024 + lane * 16);
        wl[ni] = *(const bf16x8*)((const char*)wfrag + (size_t)(i * 28 + ni * 2 + 1) * 1024 + lane * 16);
      }
      #pragma unroll
      for (int mi = 0; mi < 4; ++mi)
        #pragma unroll
        for (int ni = 0; ni < 4; ++ni)
          acc[mi][ni] = __builtin_amdgcn_mfma_f32_16x16x32_bf16(ah[mi], wh[ni], acc[mi][ni], 0, 0, 0);
      #pragma unroll
      for (int mi = 0; mi < 4; ++mi)
        #pragma unroll
        for (int ni = 0; ni < 4; ++ni)
          acc[mi][ni] = __builtin_amdgcn_mfma_f32_16x16x32_bf16(ah[mi], wl[ni], acc[mi][ni], 0, 0, 0);
      #pragma unroll
      for (int mi = 0; mi < 4; ++mi)
        #pragma unroll
        for (int ni = 0; ni < 4; ++ni)
          acc[mi][ni] = __builtin_amdgcn_mfma_f32_16x16x32_bf16(al[mi], wh[ni], acc[mi][ni], 0, 0, 0);

      // write H1: relu + split, swizzled scatter
      #pragma unroll
      for (int mi = 0; mi < 4; ++mi)
        #pragma unroll
        for (int ni = 0; ni < 4; ++ni)
          #pragma unroll
          for (int r = 0; r < 4; ++r) {
            float v = fmaxf(acc[mi][ni][r], 0.f);
            unsigned short h, l;
            split_bf16(v, h, l);
            int sl = w * 64 + mi * 16 + g * 4 + r;
            int swz = (ni * 2 + (c >> 3)) ^ (sl & 7);
            int off = sl * 128 + swz * 16 + (c & 7) * 2;
            *(short*)(Hsh[0] + off) = (short)h;
            *(short*)(Hsh[1] + off) = (short)l;
          }
    }
    __syncthreads();

    // ---- L2: [128x64] @ [64x64]  (read all A-frags, barrier, then compute+write)
    {
      bf16x8 ah[2][4], al[2][4];
      #pragma unroll
      for (int ki = 0; ki < 2; ++ki)
        #pragma unroll
        for (int mi = 0; mi < 4; ++mi) {
          int sl = w * 64 + mi * 16 + c;
          int swz = (ki * 4 + g) ^ (sl & 7);
          ah[ki][mi] = *(const bf16x8*)(Hsh[0] + sl * 128 + swz * 16);
          al[ki][mi] = *(const bf16x8*)(Hsh[1] + sl * 128 + swz * 16);
        }
      __syncthreads();

      #pragma unroll
      for (int ni = 0; ni < 4; ++ni) {
        float bv = b1[i * 64 + ni * 16 + c];
        #pragma unroll
        for (int mi = 0; mi < 4; ++mi) acc[mi][ni] = f32x4{bv, bv, bv, bv};
      }
      #pragma unroll
      for (int ki = 0; ki < 2; ++ki) {
        bf16x8 wh[4], wl[4];
        #pragma unroll
        for (int ni = 0; ni < 4; ++ni) {
          wh[ni] = *(const bf16x8*)((const char*)wfrag + (size_t)(i * 28 + 8 + ki * 8 + ni * 2 + 0) * 1024 + lane * 16);
          wl[ni] = *(const bf16x8*)((const char*)wfrag + (size_t)(i * 28 + 8 + ki * 8 + ni * 2 + 1) * 1024 + lane * 16);
        }
        #pragma unroll
        for (int mi = 0; mi < 4; ++mi)
          #pragma unroll
          for (int ni = 0; ni < 4; ++ni)
            acc[mi][ni] = __builtin_amdgcn_mfma_f32_16x16x32_bf16(ah[ki][mi], wh[ni], acc[mi][ni], 0, 0, 0);
        #pragma unroll
        for (int mi = 0; mi < 4; ++mi)
          #pragma unroll
          for (int ni = 0; ni < 4; ++ni)
            acc[mi][ni] = __builtin_amdgcn_mfma_f32_16x16x32_bf16(ah[ki][mi], wl[ni], acc[mi][ni], 0, 0, 0);
        #pragma unroll
        for (int mi = 0; mi < 4; ++mi)
          #pragma unroll
          for (int ni = 0; ni < 4; ++ni)
            acc[mi][ni] = __builtin_amdgcn_mfma_f32_16x16x32_bf16(al[ki][mi], wh[ni], acc[mi][ni], 0, 0, 0);
      }

      // write H2 (safe: all waves passed the read barrier)
      #pragma unroll
      for (int mi = 0; mi < 4; ++mi)
        #pragma unroll
        for (int ni = 0; ni < 4; ++ni)
          #pragma unroll
          for (int r = 0; r < 4; ++r) {
            float v = fmaxf(acc[mi][ni][r], 0.f);
            unsigned short h, l;
            split_bf16(v, h, l);
            int sl = w * 64 + mi * 16 + g * 4 + r;
            int swz = (ni * 2 + (c >> 3)) ^ (sl & 7);
            int off = sl * 128 + swz * 16 + (c & 7) * 2;
            *(short*)(Hsh[0] + off) = (short)h;
            *(short*)(Hsh[1] + off) = (short)l;
          }
    }
    __syncthreads();

    // ---- L3: [128x64] @ [64x16(pad)]  -> O [128][20] f32 (in UO region)
    {
      f32x4 acc3[4];
      float bv = (c < 8) ? b2[i * 8 + c] : 0.f;
      #pragma unroll
      for (int mi = 0; mi < 4; ++mi) acc3[mi] = f32x4{bv, bv, bv, bv};
      #pragma unroll
      for (int ki = 0; ki < 2; ++ki) {
        bf16x8 a_h[4], a_l[4];
        #pragma unroll
        for (int mi = 0; mi < 4; ++mi) {
          int sl = w * 64 + mi * 16 + c;
          int swz = (ki * 4 + g) ^ (sl & 7);
          a_h[mi] = *(const bf16x8*)(Hsh[0] + sl * 128 + swz * 16);
          a_l[mi] = *(const bf16x8*)(Hsh[1] + sl * 128 + swz * 16);
        }
        bf16x8 wh2 = *(const bf16x8*)((const char*)wfrag + (size_t)(i * 28 + 24 + ki * 2 + 0) * 1024 + lane * 16);
        bf16x8 wl2 = *(const bf16x8*)((const char*)wfrag + (size_t)(i * 28 + 24 + ki * 2 + 1) * 1024 + lane * 16);
        #pragma unroll
        for (int mi = 0; mi < 4; ++mi)
          acc3[mi] = __builtin_amdgcn_mfma_f32_16x16x32_bf16(a_h[mi], wh2, acc3[mi], 0, 0, 0);
        #pragma unroll
        for (int mi = 0; mi < 4; ++mi)
          acc3[mi] = __builtin_amdgcn_mfma_f32_16x16x32_bf16(a_h[mi], wl2, acc3[mi], 0, 0, 0);
        #pragma unroll
        for (int mi = 0; mi < 4; ++mi)
          acc3[mi] = __builtin_amdgcn_mfma_f32_16x16x32_bf16(a_l[mi], wh2, acc3[mi], 0, 0, 0);
      }
      // O scatter (only cols 0..15 written; epilogue reads 0..7)
      #pragma unroll
      for (int mi = 0; mi < 4; ++mi)
        #pragma unroll
        for (int r = 0; r < 4; ++r) {
          int sl = w * 64 + mi * 16 + g * 4 + r;
          *(float*)(UO + (sl * 20 + c) * 4) = acc3[mi][r];
        }
    }
    __syncthreads();

    // ---- epilogue: thread t reads its o row, updates x, logdet
    {
      const float4 o0 = *(const float4*)(UO + t * 80);
      const float4 o1 = *(const float4*)(UO + t * 80 + 16);
      float sv0 = tanhf(o0.x), sv1 = tanhf(o0.y), sv2 = tanhf(o0.z), sv3 = tanhf(o0.w);
      x[tr0 + 0] = x[tr0 + 0] * expf(sv0) + o1.x;
      x[tr0 + 1] = x[tr0 + 1] * expf(sv1) + o1.y;
      x[tr0 + 2] = x[tr0 + 2] * expf(sv2) + o1.z;
      x[tr0 + 3] = x[tr0 + 3] * expf(sv3) + o1.w;
      logdet += sv0 + sv1 + sv2 + sv3;
    }
    __syncthreads();  // protect UO until next-iteration U write
  }

  float ss = 0.f;
  #pragma unroll
  for (int q = 0; q < 8; ++q) ss += x[q] * x[q];
  out[s] = -0.5f * ss - 7.3515082656373810f + logdet;
}

// ---------------------------------------------------------------------------
extern "C" void kernel_launch(void* const* d_in, const int* in_sizes, int n_in,
                              void* d_out, int out_size, void* d_ws, size_t ws_size,
                              hipStream_t stream) {
  const float* latent  = (const float*)d_in[0];
  const float* koopman = (const float*)d_in[1];
  const float* comm    = (const float*)d_in[2];
  const float* W0      = (const float*)d_in[3];
  const float* b0      = (const float*)d_in[4];
  const float* W1      = (const float*)d_in[5];
  const float* b1      = (const float*)d_in[6];
  const float* W2      = (const float*)d_in[7];
  const float* b2      = (const float*)d_in[8];
  float* out = (float*)d_out;

  float*    graphs_ws = (float*)d_ws;                        // 8 KB
  int*      cls_ws    = (int*)((char*)d_ws + 8192);          // 16 KB
  unsigned* wfrag_ws  = (unsigned*)((char*)d_ws + 24576);    // 84 KB

  eig_filter_kernel<<<1, 256, 0, stream>>>(koopman, graphs_ws);
  argmax_kernel<<<16, 256, 0, stream>>>(comm, cls_ws, 4096);
  wpack_kernel<<<21, 256, 0, stream>>>(W0, W1, W2, wfrag_ws);

  const int total = 32 * 4096 * 16;  // 2,097,152 samples
  causal_mfma_kernel<<<total / SPB, SPB, 0, stream>>>(
      latent, graphs_ws, cls_ws, wfrag_ws, b0, b1, b2, out);
}

// Round 3
// 302.037 us; speedup vs baseline: 4.4007x; 3.0300x over previous
//
#include <hip/hip_runtime.h>
#include <hip/hip_bf16.h>

typedef __attribute__((ext_vector_type(8))) short     bf16x8;
typedef __attribute__((ext_vector_type(4))) float     f32x4;
typedef __attribute__((ext_vector_type(4))) unsigned  u32x4;

// ---------------------------------------------------------------------------
// helpers
// ---------------------------------------------------------------------------
__device__ inline unsigned short bf16_rn(float x) {
  unsigned u = __float_as_uint(x);
  unsigned r = (u + 0x7FFFu + ((u >> 16) & 1u)) >> 16;
  return (unsigned short)r;
}
__device__ inline void split_bf16(float x, unsigned short& h, unsigned short& l) {
  h = bf16_rn(x);
  float hf = __uint_as_float(((unsigned)h) << 16);
  l = bf16_rn(x - hf);
}
__device__ inline unsigned cvt_pk_bf16(float a, float b) {
  unsigned r;
  asm("v_cvt_pk_bf16_f32 %0, %1, %2" : "=v"(r) : "v"(a), "v"(b));
  return r;  // low16 = bf16(a), high16 = bf16(b)
}
__device__ inline void wfence() {  // intra-wave LDS ordering (wave-private regions)
  asm volatile("s_waitcnt lgkmcnt(0)" ::: "memory");
}
__device__ inline float tanh_fast(float v) {
  float vv = fminf(fmaxf(v, -15.f), 15.f);
  float e = __expf(2.f * vv);
  return (e - 1.f) * __frcp_rn(e + 1.f);
}

// ---------------------------------------------------------------------------
// Kernel 1: eigen-filtered Koopman graphs. 32 blocks x 64 threads (1 wave),
// block b handles matrix b. Same math as round-2 (known-good), element-parallel.
// ---------------------------------------------------------------------------
__global__ __launch_bounds__(64) void eig_filter_kernel(
    const float* __restrict__ Kt, float* __restrict__ Gout)
{
  const int b = blockIdx.x;
  const int t = threadIdx.x;
  const int row = t >> 3, col = t & 7;

  __shared__ double Kd[64];
  __shared__ double Pw[2][64];
  __shared__ double psum[8];
  __shared__ double coefs[9];
  __shared__ double rts[16];
  __shared__ double Gpart[64][8];

  Kd[t] = (double)Kt[b * 64 + t];
  __syncthreads();
  Pw[0][t] = Kd[t];
  __syncthreads();

  // power sums p_k = tr(K^k)
  int cur = 0;
  for (int p = 1; p <= 8; ++p) {
    if (t == 0) {
      double tr = 0.0;
      for (int d = 0; d < 8; ++d) tr += Pw[cur][d * 9];
      psum[p - 1] = tr;
    }
    if (p < 8) {
      double sacc = 0.0;
      for (int k = 0; k < 8; ++k) sacc += Pw[cur][row * 8 + k] * Kd[k * 8 + col];
      Pw[cur ^ 1][t] = sacc;
    }
    __syncthreads();
    cur ^= 1;
  }

  // Newton's identities
  if (t == 0) {
    double a[9];
    a[0] = 1.0;
    for (int k = 1; k <= 8; ++k) {
      double ssum = psum[k - 1];
      for (int i = 1; i < k; ++i) ssum += a[i] * psum[k - i - 1];
      a[k] = -ssum / (double)k;
    }
    for (int k = 0; k <= 8; ++k) coefs[k] = a[k];
  }
  __syncthreads();

  double a8[9];
  #pragma unroll
  for (int k = 0; k <= 8; ++k) a8[k] = coefs[k];

  // Durand-Kerner on lanes 0..7
  if (t < 8) {
    double zre = 1.0, zim = 0.0;
    for (int q = 0; q <= t; ++q) {
      double t1 = zre * 0.4 - zim * 0.9;
      double t2 = zre * 0.9 + zim * 0.4;
      zre = t1; zim = t2;
    }
    for (int it = 0; it < 120; ++it) {
      double pre = a8[0], pim = 0.0;
      #pragma unroll
      for (int k = 1; k <= 8; ++k) {
        double t1 = pre * zre - pim * zim + a8[k];
        double t2 = pre * zim + pim * zre;
        pre = t1; pim = t2;
      }
      double dre = 1.0, dim = 0.0;
      for (int j = 0; j < 8; ++j) {
        double ore = __shfl(zre, j, 64);
        double oim = __shfl(zim, j, 64);
        if (j != t) {
          double sre = zre - ore, sim = zim - oim;
          double t1 = dre * sre - dim * sim;
          double t2 = dre * sim + dim * sre;
          dre = t1; dim = t2;
        }
      }
      double d2 = dre * dre + dim * dim;
      if (d2 < 1e-60) d2 = 1e-60;
      double qre = (pre * dre + pim * dim) / d2;
      double qim = (pim * dre - pre * dim) / d2;
      zre -= qre; zim -= qim;
    }
    rts[t] = zre; rts[8 + t] = zim;
  }
  __syncthreads();

  double lre[8], lim[8];
  #pragma unroll
  for (int j = 0; j < 8; ++j) { lre[j] = rts[j]; lim[j] = rts[8 + j]; }

  // mask + fallback
  bool keep[8];
  bool any = false;
  #pragma unroll
  for (int j = 0; j < 8; ++j) {
    double sre = lre[j] + 1e-10, sim = lim[j] + 1e-10;
    double amod = sqrt(sre * sre + sim * sim);
    keep[j] = (amod <= 1.1) && (amod >= 0.9);
    any = any || keep[j];
  }
  #pragma unroll
  for (int j = 0; j < 8; ++j) if (!any) keep[j] = true;

  // Lagrange: thread (r = t>>3, myrow = t&7) computes row myrow of M_r
  const int r = t >> 3, myrow = t & 7;
  const int first = (r == 0) ? 1 : 0;
  double vre[8], vim[8];
  #pragma unroll
  for (int cc = 0; cc < 8; ++cc) {
    vre[cc] = Kd[myrow * 8 + cc] - ((myrow == cc) ? lre[first] : 0.0);
    vim[cc] = (myrow == cc) ? -lim[first] : 0.0;
  }
  #pragma unroll
  for (int j = 0; j < 8; ++j) {
    if (j == r || j == first) continue;
    double nre[8], nim[8];
    #pragma unroll
    for (int cc = 0; cc < 8; ++cc) {
      double are = 0.0, aim = 0.0;
      #pragma unroll
      for (int k = 0; k < 8; ++k) {
        double bre = Kd[k * 8 + cc] - ((k == cc) ? lre[j] : 0.0);
        double bim = (k == cc) ? -lim[j] : 0.0;
        are += vre[k] * bre - vim[k] * bim;
        aim += vre[k] * bim + vim[k] * bre;
      }
      nre[cc] = are; nim[cc] = aim;
    }
    #pragma unroll
    for (int cc = 0; cc < 8; ++cc) { vre[cc] = nre[cc]; vim[cc] = nim[cc]; }
  }

  // c_r = f(lambda_r) / prod_{j!=r}(lambda_r - lambda_j)
  double dre = 1.0, dim = 0.0;
  #pragma unroll
  for (int j = 0; j < 8; ++j) {
    if (j == r) continue;
    double ure = lre[r] - lre[j], uim = lim[r] - lim[j];
    double t1 = dre * ure - dim * uim;
    double t2 = dre * uim + dim * ure;
    dre = t1; dim = t2;
  }
  double numre = keep[r] ? (lre[r] + 1e-10) : 0.0;
  double numim = keep[r] ? (lim[r] + 1e-10) : 0.0;
  double dd = dre * dre + dim * dim;
  if (dd < 1e-300) dd = 1e-300;
  double cre = (numre * dre + numim * dim) / dd;
  double cim = (numim * dre - numre * dim) / dd;

  #pragma unroll
  for (int cc = 0; cc < 8; ++cc)
    Gpart[t][cc] = cre * vre[cc] - cim * vim[cc];
  __syncthreads();

  double sum = 0.0;
  #pragma unroll
  for (int rr = 0; rr < 8; ++rr) sum += Gpart[rr * 8 + (t >> 3)][t & 7];
  Gout[b * 64 + t] = (float)sum;
}

// ---------------------------------------------------------------------------
// Kernel 2: community argmax
// ---------------------------------------------------------------------------
__global__ __launch_bounds__(256) void argmax_kernel(
    const float* __restrict__ comm, int* __restrict__ cls, int N)
{
  int n = blockIdx.x * 256 + threadIdx.x;
  if (n >= N) return;
  const float* rowp = comm + n * 32;
  float best = rowp[0];
  int bi = 0;
  #pragma unroll
  for (int c = 1; c < 32; ++c) {
    float v = rowp[c];
    if (v > best) { best = v; bi = c; }
  }
  cls[n] = bi;
}

// ---------------------------------------------------------------------------
// Kernel 3: pack W^T as MFMA A-fragments (hi/lo planes), K-slot-permuted.
// A-frag: lane (c=l&15, g=l>>4) elem j holds W[k_orig][n = 16*nb + c], where
// for layers 2,3:  k_orig = 32*kb + 16*bit2(j) + 4*g + 2*bit1(j) + bit0(j)
// for layer 1:     k_orig = 8*g + j (natural; B built natural from u).
// Frag table per block i (28): L0: nb*2+pl (8) | L1: 8+kb*8+nb*2+pl (16)
//                              | L2: 24+kb*2+pl (4).  1KB per frag.
// ---------------------------------------------------------------------------
__global__ __launch_bounds__(256) void wpack_kernel(
    const float* __restrict__ W0, const float* __restrict__ W1,
    const float* __restrict__ W2, unsigned* __restrict__ wfrag)
{
  int gid = blockIdx.x * 256 + threadIdx.x;
  if (gid >= 84 * 64) return;
  int fid = gid >> 6, lane = gid & 63;
  int i = fid / 28, fl = fid % 28;
  int c = lane & 15, g = lane >> 4;

  unsigned short vals[8];
  #pragma unroll
  for (int j = 0; j < 8; ++j) {
    float v = 0.f;
    int plane;
    if (fl < 8) {
      int nb = fl >> 1; plane = fl & 1;
      int k = 8 * g + j;  // natural
      if (k < 12) v = W0[i * 768 + k * 64 + 16 * nb + c];
    } else if (fl < 24) {
      int q = fl - 8; int kb = q >> 3, nb = (q >> 1) & 3; plane = q & 1;
      int k = 32 * kb + 16 * ((j >> 2) & 1) + 4 * g + 2 * ((j >> 1) & 1) + (j & 1);
      v = W1[i * 4096 + k * 64 + 16 * nb + c];
    } else {
      int q = fl - 24; int kb = q >> 1; plane = q & 1;
      int k = 32 * kb + 16 * ((j >> 2) & 1) + 4 * g + 2 * ((j >> 1) & 1) + (j & 1);
      if (c < 8) v = W2[i * 512 + k * 8 + c];
    }
    unsigned short h, l;
    split_bf16(v, h, l);
    vals[j] = plane ? l : h;
  }
  u32x4 o;
  #pragma unroll
  for (int tt = 0; tt < 4; ++tt)
    o[tt] = (unsigned)vals[2 * tt] | ((unsigned)vals[2 * tt + 1] << 16);
  *(u32x4*)(wfrag + fid * 256 + lane * 4) = o;
}

// ---------------------------------------------------------------------------
// Kernel 4: main. 256 thr = 4 INDEPENDENT waves (no __syncthreads).
// Per wave: 64 samples. A = W^T (weights, hi/lo), B = activations^T (bf16),
// D = next activations^T. D->B is pure register renaming via the K-perm.
// Wave-private 2KB LDS only for U (input exchange) and O (output gather).
// ---------------------------------------------------------------------------
#define SPB 256

__global__ __launch_bounds__(256) void causal_mfma_kernel(
    const float* __restrict__ latent, const float* __restrict__ graphs,
    const int* __restrict__ cls, const unsigned* __restrict__ wfrag,
    const float* __restrict__ b0, const float* __restrict__ b1,
    const float* __restrict__ b2, float* __restrict__ out)
{
  __shared__ char LW[4][2048];

  const int t = threadIdx.x;
  const int lane = t & 63;
  const int w = t >> 6;
  const int c = lane & 15;
  const int g = lane >> 4;
  const int s = blockIdx.x * SPB + t;
  char* my = LW[w];

  float x[8];
  {
    const float4 xa = *(const float4*)(latent + (size_t)s * 8);
    const float4 xb = *(const float4*)(latent + (size_t)s * 8 + 4);
    x[0] = xa.x; x[1] = xa.y; x[2] = xa.z; x[3] = xa.w;
    x[4] = xb.x; x[5] = xb.y; x[6] = xb.z; x[7] = xb.w;
  }
  float par[8];
  {
    const int n = (s >> 4) & 4095;
    const float* G = graphs + cls[n] * 64;
    #pragma unroll
    for (int e = 0; e < 8; ++e) par[e] = 0.f;
    #pragma unroll
    for (int d = 0; d < 8; ++d) {
      const float xd = x[d];
      const float4 g0 = *(const float4*)(G + d * 8);
      const float4 g1 = *(const float4*)(G + d * 8 + 4);
      par[0] += xd * g0.x; par[1] += xd * g0.y; par[2] += xd * g0.z; par[3] += xd * g0.w;
      par[4] += xd * g1.x; par[5] += xd * g1.y; par[6] += xd * g1.z; par[7] += xd * g1.w;
    }
  }
  float logdet = 0.f;

  #pragma unroll
  for (int i = 0; i < 3; ++i) {
    const int in0 = (i & 1) ? 4 : 0;
    const int tr0 = (i & 1) ? 0 : 4;

    // ---- U: thread packs u[12] -> bf16 dword row; wave-internal exchange
    {
      float u[12];
      #pragma unroll
      for (int q = 0; q < 4; ++q) u[q] = x[in0 + q];
      #pragma unroll
      for (int q = 0; q < 8; ++q) u[4 + q] = par[q];
      u32x4 lo4, hi4;
      #pragma unroll
      for (int q = 0; q < 4; ++q) lo4[q] = cvt_pk_bf16(u[2 * q], u[2 * q + 1]);
      hi4[0] = cvt_pk_bf16(u[8], u[9]);
      hi4[1] = cvt_pk_bf16(u[10], u[11]);
      hi4[2] = 0; hi4[3] = 0;
      wfence();  // previous-iter O reads complete before overwrite
      *(u32x4*)(my + lane * 32) = lo4;
      *(u32x4*)(my + lane * 32 + 16) = hi4;
      wfence();
    }
    u32x4 B1[4];
    #pragma unroll
    for (int mb = 0; mb < 4; ++mb) {
      u32x4 z = {0u, 0u, 0u, 0u};
      B1[mb] = (g < 2) ? *(const u32x4*)(my + (16 * mb + c) * 32 + g * 16) : z;
    }

    // ---- L1: D1 = W0^T @ U^T  (K=32, 12 real)
    f32x4 acc[4][4];
    #pragma unroll
    for (int nb = 0; nb < 4; ++nb) {
      f32x4 bv = *(const f32x4*)(b0 + i * 64 + nb * 16 + g * 4);
      #pragma unroll
      for (int mb = 0; mb < 4; ++mb) acc[nb][mb] = bv;
    }
    #pragma unroll
    for (int pl = 0; pl < 2; ++pl)
      #pragma unroll
      for (int nb = 0; nb < 4; ++nb) {
        bf16x8 A = *(const bf16x8*)((const char*)wfrag +
                    (size_t)(i * 28 + nb * 2 + pl) * 1024 + lane * 16);
        #pragma unroll
        for (int mb = 0; mb < 4; ++mb)
          acc[nb][mb] = __builtin_amdgcn_mfma_f32_16x16x32_bf16(
              A, __builtin_bit_cast(bf16x8, B1[mb]), acc[nb][mb], 0, 0, 0);
      }

    // ---- relu + pack -> B2 (pure in-lane renaming, K-perm)
    unsigned P[4][4][2];
    #pragma unroll
    for (int nb = 0; nb < 4; ++nb)
      #pragma unroll
      for (int mb = 0; mb < 4; ++mb) {
        float h0 = fmaxf(acc[nb][mb][0], 0.f);
        float h1 = fmaxf(acc[nb][mb][1], 0.f);
        float h2 = fmaxf(acc[nb][mb][2], 0.f);
        float h3 = fmaxf(acc[nb][mb][3], 0.f);
        P[nb][mb][0] = cvt_pk_bf16(h0, h1);
        P[nb][mb][1] = cvt_pk_bf16(h2, h3);
      }
    u32x4 B2[2][4];
    #pragma unroll
    for (int kb = 0; kb < 2; ++kb)
      #pragma unroll
      for (int mb = 0; mb < 4; ++mb)
        B2[kb][mb] = u32x4{P[2 * kb][mb][0], P[2 * kb][mb][1],
                           P[2 * kb + 1][mb][0], P[2 * kb + 1][mb][1]};

    // ---- L2: D2 = W1^T @ H1^T  (K=64)
    #pragma unroll
    for (int nb = 0; nb < 4; ++nb) {
      f32x4 bv = *(const f32x4*)(b1 + i * 64 + nb * 16 + g * 4);
      #pragma unroll
      for (int mb = 0; mb < 4; ++mb) acc[nb][mb] = bv;
    }
    #pragma unroll
    for (int kb = 0; kb < 2; ++kb)
      #pragma unroll
      for (int pl = 0; pl < 2; ++pl)
        #pragma unroll
        for (int nb = 0; nb < 4; ++nb) {
          bf16x8 A = *(const bf16x8*)((const char*)wfrag +
                      (size_t)(i * 28 + 8 + kb * 8 + nb * 2 + pl) * 1024 + lane * 16);
          #pragma unroll
          for (int mb = 0; mb < 4; ++mb)
            acc[nb][mb] = __builtin_amdgcn_mfma_f32_16x16x32_bf16(
                A, __builtin_bit_cast(bf16x8, B2[kb][mb]), acc[nb][mb], 0, 0, 0);
        }

    // ---- relu + pack -> B3
    #pragma unroll
    for (int nb = 0; nb < 4; ++nb)
      #pragma unroll
      for (int mb = 0; mb < 4; ++mb) {
        float h0 = fmaxf(acc[nb][mb][0], 0.f);
        float h1 = fmaxf(acc[nb][mb][1], 0.f);
        float h2 = fmaxf(acc[nb][mb][2], 0.f);
        float h3 = fmaxf(acc[nb][mb][3], 0.f);
        P[nb][mb][0] = cvt_pk_bf16(h0, h1);
        P[nb][mb][1] = cvt_pk_bf16(h2, h3);
      }
    u32x4 B3[2][4];
    #pragma unroll
    for (int kb = 0; kb < 2; ++kb)
      #pragma unroll
      for (int mb = 0; mb < 4; ++mb)
        B3[kb][mb] = u32x4{P[2 * kb][mb][0], P[2 * kb][mb][1],
                           P[2 * kb + 1][mb][0], P[2 * kb + 1][mb][1]};

    // ---- L3: O^T = W2^T @ H2^T  (M=16, 8 real rows)
    f32x4 acc3[4];
    {
      f32x4 bv3 = {0.f, 0.f, 0.f, 0.f};
      if (g < 2) bv3 = *(const f32x4*)(b2 + i * 8 + g * 4);
      #pragma unroll
      for (int mb = 0; mb < 4; ++mb) acc3[mb] = bv3;
    }
    #pragma unroll
    for (int kb = 0; kb < 2; ++kb)
      #pragma unroll
      for (int pl = 0; pl < 2; ++pl) {
        bf16x8 A = *(const bf16x8*)((const char*)wfrag +
                    (size_t)(i * 28 + 24 + kb * 2 + pl) * 1024 + lane * 16);
        #pragma unroll
        for (int mb = 0; mb < 4; ++mb)
          acc3[mb] = __builtin_amdgcn_mfma_f32_16x16x32_bf16(
              A, __builtin_bit_cast(bf16x8, B3[kb][mb]), acc3[mb], 0, 0, 0);
      }

    // ---- O: wave-internal gather, then per-thread epilogue
    wfence();  // B1 reads (same region) complete
    if (g < 2) {
      #pragma unroll
      for (int mb = 0; mb < 4; ++mb)
        *(f32x4*)(my + (16 * mb + c) * 32 + g * 16) = acc3[mb];
    }
    wfence();
    {
      const float4 o0 = *(const float4*)(my + lane * 32);
      const float4 o1 = *(const float4*)(my + lane * 32 + 16);
      float sv0 = tanh_fast(o0.x), sv1 = tanh_fast(o0.y);
      float sv2 = tanh_fast(o0.z), sv3 = tanh_fast(o0.w);
      x[tr0 + 0] = x[tr0 + 0] * __expf(sv0) + o1.x;
      x[tr0 + 1] = x[tr0 + 1] * __expf(sv1) + o1.y;
      x[tr0 + 2] = x[tr0 + 2] * __expf(sv2) + o1.z;
      x[tr0 + 3] = x[tr0 + 3] * __expf(sv3) + o1.w;
      logdet += sv0 + sv1 + sv2 + sv3;
    }
  }

  float ss = 0.f;
  #pragma unroll
  for (int q = 0; q < 8; ++q) ss += x[q] * x[q];
  out[s] = -0.5f * ss - 7.3515082656373810f + logdet;
}

// ---------------------------------------------------------------------------
extern "C" void kernel_launch(void* const* d_in, const int* in_sizes, int n_in,
                              void* d_out, int out_size, void* d_ws, size_t ws_size,
                              hipStream_t stream) {
  const float* latent  = (const float*)d_in[0];
  const float* koopman = (const float*)d_in[1];
  const float* comm    = (const float*)d_in[2];
  const float* W0      = (const float*)d_in[3];
  const float* b0      = (const float*)d_in[4];
  const float* W1      = (const float*)d_in[5];
  const float* b1      = (const float*)d_in[6];
  const float* W2      = (const float*)d_in[7];
  const float* b2      = (const float*)d_in[8];
  float* out = (float*)d_out;

  float*    graphs_ws = (float*)d_ws;                        // 8 KB
  int*      cls_ws    = (int*)((char*)d_ws + 8192);          // 16 KB
  unsigned* wfrag_ws  = (unsigned*)((char*)d_ws + 24576);    // 84 KB

  eig_filter_kernel<<<32, 64, 0, stream>>>(koopman, graphs_ws);
  argmax_kernel<<<16, 256, 0, stream>>>(comm, cls_ws, 4096);
  wpack_kernel<<<21, 256, 0, stream>>>(W0, W1, W2, wfrag_ws);

  const int total = 32 * 4096 * 16;  // 2,097,152 samples
  causal_mfma_kernel<<<total / SPB, SPB, 0, stream>>>(
      latent, graphs_ws, cls_ws, wfrag_ws, b0, b1, b2, out);
}

// Round 4
// 204.840 us; speedup vs baseline: 6.4888x; 1.4745x over previous
//
#include <hip/hip_runtime.h>
#include <hip/hip_bf16.h>

typedef __attribute__((ext_vector_type(8))) short     bf16x8;
typedef __attribute__((ext_vector_type(4))) float     f32x4;
typedef __attribute__((ext_vector_type(4))) unsigned  u32x4;

// ---------------------------------------------------------------------------
// helpers
// ---------------------------------------------------------------------------
__device__ inline unsigned short bf16_rn(float x) {
  unsigned u = __float_as_uint(x);
  unsigned r = (u + 0x7FFFu + ((u >> 16) & 1u)) >> 16;
  return (unsigned short)r;
}
__device__ inline unsigned cvt_pk_bf16(float a, float b) {
  unsigned r;
  asm("v_cvt_pk_bf16_f32 %0, %1, %2" : "=v"(r) : "v"(a), "v"(b));
  return r;  // low16 = bf16(a), high16 = bf16(b)
}
__device__ inline void wfence() {  // intra-wave LDS ordering (wave-private regions)
  asm volatile("s_waitcnt lgkmcnt(0)" ::: "memory");
}
__device__ inline float tanh_fast(float v) {
  float vv = fminf(fmaxf(v, -15.f), 15.f);
  float e = __expf(2.f * vv);
  return (e - 1.f) * __frcp_rn(e + 1.f);
}

// ---------------------------------------------------------------------------
// Merged prologue: blocks 0..31 eig | 32..47 argmax | 48..58 wpack
// ---------------------------------------------------------------------------
__global__ __launch_bounds__(256) void prologue_kernel(
    const float* __restrict__ Kt, const float* __restrict__ comm,
    const float* __restrict__ W0, const float* __restrict__ W1,
    const float* __restrict__ W2,
    float* __restrict__ Gout, int* __restrict__ cls,
    unsigned* __restrict__ wfrag)
{
  const int b = blockIdx.x;
  const int t = threadIdx.x;

  if (b < 32) {
    // ---------------- eig-filter for matrix b (threads 0..63 compute) ------
    __shared__ double Kd[64];
    __shared__ double Pw[2][64];
    __shared__ double psum[8];
    __shared__ double coefs[9];
    __shared__ double rts[16];
    __shared__ double Gpart[64][8];

    const int tl = t & 63;
    const int row = tl >> 3, col = tl & 7;

    if (t < 64) Kd[tl] = (double)Kt[b * 64 + tl];
    __syncthreads();
    if (t < 64) Pw[0][tl] = Kd[tl];
    __syncthreads();

    int cur = 0;
    for (int p = 1; p <= 8; ++p) {
      if (t == 0) {
        double tr = 0.0;
        for (int d = 0; d < 8; ++d) tr += Pw[cur][d * 9];
        psum[p - 1] = tr;
      }
      if (p < 8 && t < 64) {
        double sacc = 0.0;
        for (int k = 0; k < 8; ++k) sacc += Pw[cur][row * 8 + k] * Kd[k * 8 + col];
        Pw[cur ^ 1][tl] = sacc;
      }
      __syncthreads();
      cur ^= 1;
    }

    if (t == 0) {
      double a[9];
      a[0] = 1.0;
      for (int k = 1; k <= 8; ++k) {
        double ssum = psum[k - 1];
        for (int i = 1; i < k; ++i) ssum += a[i] * psum[k - i - 1];
        a[k] = -ssum / (double)k;
      }
      for (int k = 0; k <= 8; ++k) coefs[k] = a[k];
    }
    __syncthreads();

    if (t < 8) {
      double a8[9];
      #pragma unroll
      for (int k = 0; k <= 8; ++k) a8[k] = coefs[k];
      double zre = 1.0, zim = 0.0;
      for (int q = 0; q <= t; ++q) {
        double t1 = zre * 0.4 - zim * 0.9;
        double t2 = zre * 0.9 + zim * 0.4;
        zre = t1; zim = t2;
      }
      for (int it = 0; it < 60; ++it) {
        double pre = a8[0], pim = 0.0;
        #pragma unroll
        for (int k = 1; k <= 8; ++k) {
          double t1 = pre * zre - pim * zim + a8[k];
          double t2 = pre * zim + pim * zre;
          pre = t1; pim = t2;
        }
        double dre = 1.0, dim = 0.0;
        for (int j = 0; j < 8; ++j) {
          double ore = __shfl(zre, j, 64);
          double oim = __shfl(zim, j, 64);
          if (j != t) {
            double sre = zre - ore, sim = zim - oim;
            double t1 = dre * sre - dim * sim;
            double t2 = dre * sim + dim * sre;
            dre = t1; dim = t2;
          }
        }
        double d2 = dre * dre + dim * dim;
        if (d2 < 1e-60) d2 = 1e-60;
        double qre = (pre * dre + pim * dim) / d2;
        double qim = (pim * dre - pre * dim) / d2;
        zre -= qre; zim -= qim;
      }
      rts[t] = zre; rts[8 + t] = zim;
    }
    __syncthreads();

    if (t < 64) {
      double lre[8], lim[8];
      #pragma unroll
      for (int j = 0; j < 8; ++j) { lre[j] = rts[j]; lim[j] = rts[8 + j]; }

      bool keep[8]; bool any = false;
      #pragma unroll
      for (int j = 0; j < 8; ++j) {
        double sre = lre[j] + 1e-10, sim = lim[j] + 1e-10;
        double amod = sqrt(sre * sre + sim * sim);
        keep[j] = (amod <= 1.1) && (amod >= 0.9);
        any = any || keep[j];
      }
      #pragma unroll
      for (int j = 0; j < 8; ++j) if (!any) keep[j] = true;

      const int r = tl >> 3, myrow = tl & 7;
      const int first = (r == 0) ? 1 : 0;
      double vre[8], vim[8];
      #pragma unroll
      for (int cc = 0; cc < 8; ++cc) {
        vre[cc] = Kd[myrow * 8 + cc] - ((myrow == cc) ? lre[first] : 0.0);
        vim[cc] = (myrow == cc) ? -lim[first] : 0.0;
      }
      #pragma unroll
      for (int j = 0; j < 8; ++j) {
        if (j == r || j == first) continue;
        double nre[8], nim[8];
        #pragma unroll
        for (int cc = 0; cc < 8; ++cc) {
          double are = 0.0, aim = 0.0;
          #pragma unroll
          for (int k = 0; k < 8; ++k) {
            double bre = Kd[k * 8 + cc] - ((k == cc) ? lre[j] : 0.0);
            double bim = (k == cc) ? -lim[j] : 0.0;
            are += vre[k] * bre - vim[k] * bim;
            aim += vre[k] * bim + vim[k] * bre;
          }
          nre[cc] = are; nim[cc] = aim;
        }
        #pragma unroll
        for (int cc = 0; cc < 8; ++cc) { vre[cc] = nre[cc]; vim[cc] = nim[cc]; }
      }

      double dre = 1.0, dim = 0.0;
      #pragma unroll
      for (int j = 0; j < 8; ++j) {
        if (j == r) continue;
        double ure = lre[r] - lre[j], uim = lim[r] - lim[j];
        double t1 = dre * ure - dim * uim;
        double t2 = dre * uim + dim * ure;
        dre = t1; dim = t2;
      }
      double numre = keep[r] ? (lre[r] + 1e-10) : 0.0;
      double numim = keep[r] ? (lim[r] + 1e-10) : 0.0;
      double dd = dre * dre + dim * dim;
      if (dd < 1e-300) dd = 1e-300;
      double cre = (numre * dre + numim * dim) / dd;
      double cim = (numim * dre - numre * dim) / dd;

      #pragma unroll
      for (int cc = 0; cc < 8; ++cc)
        Gpart[tl][cc] = cre * vre[cc] - cim * vim[cc];
    }
    __syncthreads();

    if (t < 64) {
      const int tl2 = t;
      double sum = 0.0;
      #pragma unroll
      for (int rr = 0; rr < 8; ++rr) sum += Gpart[rr * 8 + (tl2 >> 3)][tl2 & 7];
      Gout[b * 64 + tl2] = (float)sum;
    }
    return;
  }

  if (b < 48) {
    // ---------------- argmax -----------------------------------------------
    int n = (b - 32) * 256 + t;
    if (n < 4096) {
      const float* rowp = comm + n * 32;
      float best = rowp[0];
      int bi = 0;
      #pragma unroll
      for (int c = 1; c < 32; ++c) {
        float v = rowp[c];
        if (v > best) { best = v; bi = c; }
      }
      cls[n] = bi;
    }
    return;
  }

  // ---------------- wpack: 42 frags (single bf16 plane), K-slot-permuted ----
  // per block i (14): L0: nb (4) | L1: 4+kb*4+nb (8) | L2: 12+kb (2)
  {
    int gid = (b - 48) * 256 + t;
    if (gid >= 42 * 64) return;
    int fid = gid >> 6, lane = gid & 63;
    int i = fid / 14, fl = fid % 14;
    int c = lane & 15, g = lane >> 4;

    unsigned short vals[8];
    #pragma unroll
    for (int j = 0; j < 8; ++j) {
      float v = 0.f;
      if (fl < 4) {
        int nb = fl;
        int k = 8 * g + j;  // natural
        if (k < 12) v = W0[i * 768 + k * 64 + 16 * nb + c];
      } else if (fl < 12) {
        int q = fl - 4; int kb = q >> 2, nb = q & 3;
        int k = 32 * kb + 16 * ((j >> 2) & 1) + 4 * g + 2 * ((j >> 1) & 1) + (j & 1);
        v = W1[i * 4096 + k * 64 + 16 * nb + c];
      } else {
        int kb = fl - 12;
        int k = 32 * kb + 16 * ((j >> 2) & 1) + 4 * g + 2 * ((j >> 1) & 1) + (j & 1);
        if (c < 8) v = W2[i * 512 + k * 8 + c];
      }
      vals[j] = bf16_rn(v);
    }
    u32x4 o;
    #pragma unroll
    for (int tt = 0; tt < 4; ++tt)
      o[tt] = (unsigned)vals[2 * tt] | ((unsigned)vals[2 * tt + 1] << 16);
    *(u32x4*)(wfrag + fid * 256 + lane * 4) = o;
  }
}

// ---------------------------------------------------------------------------
// Main: 256 thr = 4 INDEPENDENT waves. Per wave: 64 samples.
// A = W^T (bf16, pre-permuted), B = activations^T, D = next activations^T
// (D->B pure register renaming). Bias enters as the C operand of the first
// MFMA of each chain (no init movs). Wave-private 2KB LDS for U/O exchange.
// ---------------------------------------------------------------------------
#define SPB 256

__global__ __launch_bounds__(256) void causal_mfma_kernel(
    const float* __restrict__ latent, const float* __restrict__ graphs,
    const int* __restrict__ cls, const unsigned* __restrict__ wfrag,
    const float* __restrict__ b0, const float* __restrict__ b1,
    const float* __restrict__ b2, float* __restrict__ out)
{
  __shared__ char LW[4][2048];

  const int t = threadIdx.x;
  const int lane = t & 63;
  const int w = t >> 6;
  const int c = lane & 15;
  const int g = lane >> 4;
  const int s = blockIdx.x * SPB + t;
  char* my = LW[w];

  float x[8];
  {
    const float4 xa = *(const float4*)(latent + (size_t)s * 8);
    const float4 xb = *(const float4*)(latent + (size_t)s * 8 + 4);
    x[0] = xa.x; x[1] = xa.y; x[2] = xa.z; x[3] = xa.w;
    x[4] = xb.x; x[5] = xb.y; x[6] = xb.z; x[7] = xb.w;
  }
  float par[8];
  {
    const int n = (s >> 4) & 4095;
    const float* G = graphs + cls[n] * 64;
    #pragma unroll
    for (int e = 0; e < 8; ++e) par[e] = 0.f;
    #pragma unroll
    for (int d = 0; d < 8; ++d) {
      const float xd = x[d];
      const float4 g0 = *(const float4*)(G + d * 8);
      const float4 g1 = *(const float4*)(G + d * 8 + 4);
      par[0] += xd * g0.x; par[1] += xd * g0.y; par[2] += xd * g0.z; par[3] += xd * g0.w;
      par[4] += xd * g1.x; par[5] += xd * g1.y; par[6] += xd * g1.z; par[7] += xd * g1.w;
    }
  }
  float logdet = 0.f;

  #pragma unroll
  for (int i = 0; i < 3; ++i) {
    const int in0 = (i & 1) ? 4 : 0;
    const int tr0 = (i & 1) ? 0 : 4;

    // ---- bias quads (C operands), issued early
    f32x4 bC0[4], bC1[4], bC2;
    #pragma unroll
    for (int nb = 0; nb < 4; ++nb) bC0[nb] = *(const f32x4*)(b0 + i * 64 + nb * 16 + g * 4);
    #pragma unroll
    for (int nb = 0; nb < 4; ++nb) bC1[nb] = *(const f32x4*)(b1 + i * 64 + nb * 16 + g * 4);
    {
      f32x4 z = {0.f, 0.f, 0.f, 0.f};
      bC2 = (g < 2) ? *(const f32x4*)(b2 + i * 8 + g * 4) : z;
    }

    // ---- U: pack u[12] -> bf16 row; wave-internal transpose via LDS
    {
      float u[12];
      #pragma unroll
      for (int q = 0; q < 4; ++q) u[q] = x[in0 + q];
      #pragma unroll
      for (int q = 0; q < 8; ++q) u[4 + q] = par[q];
      u32x4 lo4, hi4;
      #pragma unroll
      for (int q = 0; q < 4; ++q) lo4[q] = cvt_pk_bf16(u[2 * q], u[2 * q + 1]);
      hi4[0] = cvt_pk_bf16(u[8], u[9]);
      hi4[1] = cvt_pk_bf16(u[10], u[11]);
      hi4[2] = 0; hi4[3] = 0;
      wfence();  // previous-iter O reads complete before overwrite
      *(u32x4*)(my + lane * 32) = lo4;
      *(u32x4*)(my + lane * 32 + 16) = hi4;
      wfence();
    }
    u32x4 B1[4];
    #pragma unroll
    for (int mb = 0; mb < 4; ++mb) {
      u32x4 z = {0u, 0u, 0u, 0u};
      B1[mb] = (g < 2) ? *(const u32x4*)(my + (16 * mb + c) * 32 + g * 16) : z;
    }

    // ---- L1: D1 = W0^T @ U^T + b0  (K=32, 12 real; single MFMA per chain)
    f32x4 acc[4][4];
    #pragma unroll
    for (int nb = 0; nb < 4; ++nb) {
      bf16x8 A = *(const bf16x8*)((const char*)wfrag +
                  (size_t)(i * 14 + nb) * 1024 + lane * 16);
      #pragma unroll
      for (int mb = 0; mb < 4; ++mb)
        acc[nb][mb] = __builtin_amdgcn_mfma_f32_16x16x32_bf16(
            A, __builtin_bit_cast(bf16x8, B1[mb]), bC0[nb], 0, 0, 0);
    }

    // ---- relu + pack -> B2 (pure in-lane renaming, K-perm)
    unsigned P[4][4][2];
    #pragma unroll
    for (int nb = 0; nb < 4; ++nb)
      #pragma unroll
      for (int mb = 0; mb < 4; ++mb) {
        float h0 = fmaxf(acc[nb][mb][0], 0.f);
        float h1 = fmaxf(acc[nb][mb][1], 0.f);
        float h2 = fmaxf(acc[nb][mb][2], 0.f);
        float h3 = fmaxf(acc[nb][mb][3], 0.f);
        P[nb][mb][0] = cvt_pk_bf16(h0, h1);
        P[nb][mb][1] = cvt_pk_bf16(h2, h3);
      }
    u32x4 B2[2][4];
    #pragma unroll
    for (int kb = 0; kb < 2; ++kb)
      #pragma unroll
      for (int mb = 0; mb < 4; ++mb)
        B2[kb][mb] = u32x4{P[2 * kb][mb][0], P[2 * kb][mb][1],
                           P[2 * kb + 1][mb][0], P[2 * kb + 1][mb][1]};

    // ---- L2: D2 = W1^T @ H1^T + b1  (K=64)
    #pragma unroll
    for (int kb = 0; kb < 2; ++kb)
      #pragma unroll
      for (int nb = 0; nb < 4; ++nb) {
        bf16x8 A = *(const bf16x8*)((const char*)wfrag +
                    (size_t)(i * 14 + 4 + kb * 4 + nb) * 1024 + lane * 16);
        #pragma unroll
        for (int mb = 0; mb < 4; ++mb)
          acc[nb][mb] = __builtin_amdgcn_mfma_f32_16x16x32_bf16(
              A, __builtin_bit_cast(bf16x8, B2[kb][mb]),
              (kb == 0) ? bC1[nb] : acc[nb][mb], 0, 0, 0);
      }

    // ---- relu + pack -> B3
    #pragma unroll
    for (int nb = 0; nb < 4; ++nb)
      #pragma unroll
      for (int mb = 0; mb < 4; ++mb) {
        float h0 = fmaxf(acc[nb][mb][0], 0.f);
        float h1 = fmaxf(acc[nb][mb][1], 0.f);
        float h2 = fmaxf(acc[nb][mb][2], 0.f);
        float h3 = fmaxf(acc[nb][mb][3], 0.f);
        P[nb][mb][0] = cvt_pk_bf16(h0, h1);
        P[nb][mb][1] = cvt_pk_bf16(h2, h3);
      }
    u32x4 B3[2][4];
    #pragma unroll
    for (int kb = 0; kb < 2; ++kb)
      #pragma unroll
      for (int mb = 0; mb < 4; ++mb)
        B3[kb][mb] = u32x4{P[2 * kb][mb][0], P[2 * kb][mb][1],
                           P[2 * kb + 1][mb][0], P[2 * kb + 1][mb][1]};

    // ---- L3: O^T = W2^T @ H2^T + b2  (M=16, 8 real rows)
    f32x4 acc3[4];
    {
      bf16x8 A0 = *(const bf16x8*)((const char*)wfrag +
                   (size_t)(i * 14 + 12) * 1024 + lane * 16);
      bf16x8 A1 = *(const bf16x8*)((const char*)wfrag +
                   (size_t)(i * 14 + 13) * 1024 + lane * 16);
      #pragma unroll
      for (int mb = 0; mb < 4; ++mb) {
        f32x4 tmp = __builtin_amdgcn_mfma_f32_16x16x32_bf16(
            A0, __builtin_bit_cast(bf16x8, B3[0][mb]), bC2, 0, 0, 0);
        acc3[mb] = __builtin_amdgcn_mfma_f32_16x16x32_bf16(
            A1, __builtin_bit_cast(bf16x8, B3[1][mb]), tmp, 0, 0, 0);
      }
    }

    // ---- O: wave-internal gather, then per-thread epilogue
    wfence();  // B1 reads (same region) complete
    if (g < 2) {
      #pragma unroll
      for (int mb = 0; mb < 4; ++mb)
        *(f32x4*)(my + (16 * mb + c) * 32 + g * 16) = acc3[mb];
    }
    wfence();
    {
      const float4 o0 = *(const float4*)(my + lane * 32);
      const float4 o1 = *(const float4*)(my + lane * 32 + 16);
      float sv0 = tanh_fast(o0.x), sv1 = tanh_fast(o0.y);
      float sv2 = tanh_fast(o0.z), sv3 = tanh_fast(o0.w);
      x[tr0 + 0] = x[tr0 + 0] * __expf(sv0) + o1.x;
      x[tr0 + 1] = x[tr0 + 1] * __expf(sv1) + o1.y;
      x[tr0 + 2] = x[tr0 + 2] * __expf(sv2) + o1.z;
      x[tr0 + 3] = x[tr0 + 3] * __expf(sv3) + o1.w;
      logdet += sv0 + sv1 + sv2 + sv3;
    }
  }

  float ss = 0.f;
  #pragma unroll
  for (int q = 0; q < 8; ++q) ss += x[q] * x[q];
  out[s] = -0.5f * ss - 7.3515082656373810f + logdet;
}

// ---------------------------------------------------------------------------
extern "C" void kernel_launch(void* const* d_in, const int* in_sizes, int n_in,
                              void* d_out, int out_size, void* d_ws, size_t ws_size,
                              hipStream_t stream) {
  const float* latent  = (const float*)d_in[0];
  const float* koopman = (const float*)d_in[1];
  const float* comm    = (const float*)d_in[2];
  const float* W0      = (const float*)d_in[3];
  const float* b0      = (const float*)d_in[4];
  const float* W1      = (const float*)d_in[5];
  const float* b1      = (const float*)d_in[6];
  const float* W2      = (const float*)d_in[7];
  const float* b2      = (const float*)d_in[8];
  float* out = (float*)d_out;

  float*    graphs_ws = (float*)d_ws;                        // 8 KB
  int*      cls_ws    = (int*)((char*)d_ws + 8192);          // 16 KB
  unsigned* wfrag_ws  = (unsigned*)((char*)d_ws + 24576);    // 42 KB

  // blocks: 0..31 eig | 32..47 argmax | 48..58 wpack
  prologue_kernel<<<59, 256, 0, stream>>>(
      koopman, comm, W0, W1, W2, graphs_ws, cls_ws, wfrag_ws);

  const int total = 32 * 4096 * 16;  // 2,097,152 samples
  causal_mfma_kernel<<<total / SPB, SPB, 0, stream>>>(
      latent, graphs_ws, cls_ws, wfrag_ws, b0, b1, b2, out);
}

// Round 5
// 174.683 us; speedup vs baseline: 7.6090x; 1.1726x over previous
//
#include <hip/hip_runtime.h>
#include <hip/hip_bf16.h>

typedef __attribute__((ext_vector_type(8))) short     bf16x8;
typedef __attribute__((ext_vector_type(4))) float     f32x4;
typedef __attribute__((ext_vector_type(4))) unsigned  u32x4;

// ---------------------------------------------------------------------------
// helpers
// ---------------------------------------------------------------------------
__device__ inline unsigned short bf16_rn(float x) {
  unsigned u = __float_as_uint(x);
  unsigned r = (u + 0x7FFFu + ((u >> 16) & 1u)) >> 16;
  return (unsigned short)r;
}
__device__ inline unsigned cvt_pk_bf16(float a, float b) {
  unsigned r;
  asm("v_cvt_pk_bf16_f32 %0, %1, %2" : "=v"(r) : "v"(a), "v"(b));
  return r;  // low16 = bf16(a), high16 = bf16(b)
}
__device__ inline void wfence() {  // intra-wave LDS ordering (wave-private regions)
  asm volatile("s_waitcnt lgkmcnt(0)" ::: "memory");
}
__device__ inline float tanh_fast(float v) {
  float vv = fminf(fmaxf(v, -15.f), 15.f);
  float e = __expf(2.f * vv);
  return (e - 1.f) * __frcp_rn(e + 1.f);
}

// ---------------------------------------------------------------------------
// Merged prologue: blocks 0..31 eig | 32..47 argmax | 48..58 wpack
// ---------------------------------------------------------------------------
__global__ __launch_bounds__(256) void prologue_kernel(
    const float* __restrict__ Kt, const float* __restrict__ comm,
    const float* __restrict__ W0, const float* __restrict__ W1,
    const float* __restrict__ W2,
    float* __restrict__ Gout, int* __restrict__ cls,
    unsigned* __restrict__ wfrag)
{
  const int b = blockIdx.x;
  const int t = threadIdx.x;

  if (b < 32) {
    // ---------------- eig-filter for matrix b (threads 0..63 compute) ------
    __shared__ double Kd[64];
    __shared__ double Pw[2][64];
    __shared__ double psum[8];
    __shared__ double coefs[9];
    __shared__ double rts[16];
    __shared__ double Gpart[64][8];

    const int tl = t & 63;
    const int row = tl >> 3, col = tl & 7;

    if (t < 64) Kd[tl] = (double)Kt[b * 64 + tl];
    __syncthreads();
    if (t < 64) Pw[0][tl] = Kd[tl];
    __syncthreads();

    int cur = 0;
    for (int p = 1; p <= 8; ++p) {
      if (t == 0) {
        double tr = 0.0;
        for (int d = 0; d < 8; ++d) tr += Pw[cur][d * 9];
        psum[p - 1] = tr;
      }
      if (p < 8 && t < 64) {
        double sacc = 0.0;
        for (int k = 0; k < 8; ++k) sacc += Pw[cur][row * 8 + k] * Kd[k * 8 + col];
        Pw[cur ^ 1][tl] = sacc;
      }
      __syncthreads();
      cur ^= 1;
    }

    if (t == 0) {
      double a[9];
      a[0] = 1.0;
      for (int k = 1; k <= 8; ++k) {
        double ssum = psum[k - 1];
        for (int i = 1; i < k; ++i) ssum += a[i] * psum[k - i - 1];
        a[k] = -ssum / (double)k;
      }
      for (int k = 0; k <= 8; ++k) coefs[k] = a[k];
    }
    __syncthreads();

    if (t < 8) {
      double a8[9];
      #pragma unroll
      for (int k = 0; k <= 8; ++k) a8[k] = coefs[k];
      double zre = 1.0, zim = 0.0;
      for (int q = 0; q <= t; ++q) {
        double t1 = zre * 0.4 - zim * 0.9;
        double t2 = zre * 0.9 + zim * 0.4;
        zre = t1; zim = t2;
      }
      for (int it = 0; it < 60; ++it) {
        double pre = a8[0], pim = 0.0;
        #pragma unroll
        for (int k = 1; k <= 8; ++k) {
          double t1 = pre * zre - pim * zim + a8[k];
          double t2 = pre * zim + pim * zre;
          pre = t1; pim = t2;
        }
        double dre = 1.0, dim = 0.0;
        for (int j = 0; j < 8; ++j) {
          double ore = __shfl(zre, j, 64);
          double oim = __shfl(zim, j, 64);
          if (j != t) {
            double sre = zre - ore, sim = zim - oim;
            double t1 = dre * sre - dim * sim;
            double t2 = dre * sim + dim * sre;
            dre = t1; dim = t2;
          }
        }
        double d2 = dre * dre + dim * dim;
        if (d2 < 1e-60) d2 = 1e-60;
        double qre = (pre * dre + pim * dim) / d2;
        double qim = (pim * dre - pre * dim) / d2;
        zre -= qre; zim -= qim;
      }
      rts[t] = zre; rts[8 + t] = zim;
    }
    __syncthreads();

    if (t < 64) {
      double lre[8], lim[8];
      #pragma unroll
      for (int j = 0; j < 8; ++j) { lre[j] = rts[j]; lim[j] = rts[8 + j]; }

      bool keep[8]; bool any = false;
      #pragma unroll
      for (int j = 0; j < 8; ++j) {
        double sre = lre[j] + 1e-10, sim = lim[j] + 1e-10;
        double amod = sqrt(sre * sre + sim * sim);
        keep[j] = (amod <= 1.1) && (amod >= 0.9);
        any = any || keep[j];
      }
      #pragma unroll
      for (int j = 0; j < 8; ++j) if (!any) keep[j] = true;

      const int r = tl >> 3, myrow = tl & 7;
      const int first = (r == 0) ? 1 : 0;
      double vre[8], vim[8];
      #pragma unroll
      for (int cc = 0; cc < 8; ++cc) {
        vre[cc] = Kd[myrow * 8 + cc] - ((myrow == cc) ? lre[first] : 0.0);
        vim[cc] = (myrow == cc) ? -lim[first] : 0.0;
      }
      #pragma unroll
      for (int j = 0; j < 8; ++j) {
        if (j == r || j == first) continue;
        double nre[8], nim[8];
        #pragma unroll
        for (int cc = 0; cc < 8; ++cc) {
          double are = 0.0, aim = 0.0;
          #pragma unroll
          for (int k = 0; k < 8; ++k) {
            double bre = Kd[k * 8 + cc] - ((k == cc) ? lre[j] : 0.0);
            double bim = (k == cc) ? -lim[j] : 0.0;
            are += vre[k] * bre - vim[k] * bim;
            aim += vre[k] * bim + vim[k] * bre;
          }
          nre[cc] = are; nim[cc] = aim;
        }
        #pragma unroll
        for (int cc = 0; cc < 8; ++cc) { vre[cc] = nre[cc]; vim[cc] = nim[cc]; }
      }

      double dre = 1.0, dim = 0.0;
      #pragma unroll
      for (int j = 0; j < 8; ++j) {
        if (j == r) continue;
        double ure = lre[r] - lre[j], uim = lim[r] - lim[j];
        double t1 = dre * ure - dim * uim;
        double t2 = dre * uim + dim * ure;
        dre = t1; dim = t2;
      }
      double numre = keep[r] ? (lre[r] + 1e-10) : 0.0;
      double numim = keep[r] ? (lim[r] + 1e-10) : 0.0;
      double dd = dre * dre + dim * dim;
      if (dd < 1e-300) dd = 1e-300;
      double cre = (numre * dre + numim * dim) / dd;
      double cim = (numim * dre - numre * dim) / dd;

      #pragma unroll
      for (int cc = 0; cc < 8; ++cc)
        Gpart[tl][cc] = cre * vre[cc] - cim * vim[cc];
    }
    __syncthreads();

    if (t < 64) {
      double sum = 0.0;
      #pragma unroll
      for (int rr = 0; rr < 8; ++rr) sum += Gpart[rr * 8 + (t >> 3)][t & 7];
      Gout[b * 64 + t] = (float)sum;
    }
    return;
  }

  if (b < 48) {
    // ---------------- argmax -----------------------------------------------
    int n = (b - 32) * 256 + t;
    if (n < 4096) {
      const float* rowp = comm + n * 32;
      float best = rowp[0];
      int bi = 0;
      #pragma unroll
      for (int c = 1; c < 32; ++c) {
        float v = rowp[c];
        if (v > best) { best = v; bi = c; }
      }
      cls[n] = bi;
    }
    return;
  }

  // ---------------- wpack: 42 frags (single bf16 plane), K-slot-permuted ----
  // per block i (14): L0: nb (4) | L1: 4+kb*4+nb (8) | L2: 12+kb (2)
  {
    int gid = (b - 48) * 256 + t;
    if (gid >= 42 * 64) return;
    int fid = gid >> 6, lane = gid & 63;
    int i = fid / 14, fl = fid % 14;
    int c = lane & 15, g = lane >> 4;

    unsigned short vals[8];
    #pragma unroll
    for (int j = 0; j < 8; ++j) {
      float v = 0.f;
      if (fl < 4) {
        int nb = fl;
        int k = 8 * g + j;  // natural
        if (k < 12) v = W0[i * 768 + k * 64 + 16 * nb + c];
      } else if (fl < 12) {
        int q = fl - 4; int kb = q >> 2, nb = q & 3;
        int k = 32 * kb + 16 * ((j >> 2) & 1) + 4 * g + 2 * ((j >> 1) & 1) + (j & 1);
        v = W1[i * 4096 + k * 64 + 16 * nb + c];
      } else {
        int kb = fl - 12;
        int k = 32 * kb + 16 * ((j >> 2) & 1) + 4 * g + 2 * ((j >> 1) & 1) + (j & 1);
        if (c < 8) v = W2[i * 512 + k * 8 + c];
      }
      vals[j] = bf16_rn(v);
    }
    u32x4 o;
    #pragma unroll
    for (int tt = 0; tt < 4; ++tt)
      o[tt] = (unsigned)vals[2 * tt] | ((unsigned)vals[2 * tt + 1] << 16);
    *(u32x4*)(wfrag + fid * 256 + lane * 4) = o;
  }
}

// ---------------------------------------------------------------------------
// Main: 256 thr = 4 INDEPENDENT waves, 64 samples/wave.
// Phased dataflow (A..E) to cap live accumulators at 8 quads:
//   A: L1 nb=0,1 -> B2k0   B: L1 nb=2,3 -> B2k1
//   C: L2 nb=0,1 -> B3k0   D: L2 nb=2,3 -> B3k1
//   E: L3 chained (A0@B3k0 + A1@B3k1)
// launch_bounds(256,3): force VGPR-only allocation, 3 waves/SIMD.
// ---------------------------------------------------------------------------
#define SPB 256

__global__ __launch_bounds__(256, 3) void causal_mfma_kernel(
    const float* __restrict__ latent, const float* __restrict__ graphs,
    const int* __restrict__ cls, const unsigned* __restrict__ wfrag,
    const float* __restrict__ b0, const float* __restrict__ b1,
    const float* __restrict__ b2, float* __restrict__ out)
{
  __shared__ char LW[4][2048];

  const int t = threadIdx.x;
  const int lane = t & 63;
  const int w = t >> 6;
  const int c = lane & 15;
  const int g = lane >> 4;
  const int s = blockIdx.x * SPB + t;
  char* my = LW[w];

  float x[8];
  {
    const float4 xa = *(const float4*)(latent + (size_t)s * 8);
    const float4 xb = *(const float4*)(latent + (size_t)s * 8 + 4);
    x[0] = xa.x; x[1] = xa.y; x[2] = xa.z; x[3] = xa.w;
    x[4] = xb.x; x[5] = xb.y; x[6] = xb.z; x[7] = xb.w;
  }
  float par[8];
  {
    const int n = (s >> 4) & 4095;
    const float* G = graphs + cls[n] * 64;
    #pragma unroll
    for (int e = 0; e < 8; ++e) par[e] = 0.f;
    #pragma unroll
    for (int d = 0; d < 8; ++d) {
      const float xd = x[d];
      const float4 g0 = *(const float4*)(G + d * 8);
      const float4 g1 = *(const float4*)(G + d * 8 + 4);
      par[0] += xd * g0.x; par[1] += xd * g0.y; par[2] += xd * g0.z; par[3] += xd * g0.w;
      par[4] += xd * g1.x; par[5] += xd * g1.y; par[6] += xd * g1.z; par[7] += xd * g1.w;
    }
  }
  float logdet = 0.f;

  #pragma unroll
  for (int i = 0; i < 3; ++i) {
    const int in0 = (i & 1) ? 4 : 0;
    const int tr0 = (i & 1) ? 0 : 4;
    const char* wbase = (const char*)wfrag + (size_t)(i * 14) * 1024 + lane * 16;

    // ---- U: pack u[12] -> bf16 row; wave-internal transpose via LDS
    {
      float u[12];
      #pragma unroll
      for (int q = 0; q < 4; ++q) u[q] = x[in0 + q];
      #pragma unroll
      for (int q = 0; q < 8; ++q) u[4 + q] = par[q];
      u32x4 lo4, hi4;
      #pragma unroll
      for (int q = 0; q < 4; ++q) lo4[q] = cvt_pk_bf16(u[2 * q], u[2 * q + 1]);
      hi4[0] = cvt_pk_bf16(u[8], u[9]);
      hi4[1] = cvt_pk_bf16(u[10], u[11]);
      hi4[2] = 0; hi4[3] = 0;
      wfence();  // previous-iter O reads complete before overwrite
      *(u32x4*)(my + lane * 32) = lo4;
      *(u32x4*)(my + lane * 32 + 16) = hi4;
      wfence();
    }
    u32x4 B1[4];
    #pragma unroll
    for (int mb = 0; mb < 4; ++mb) {
      u32x4 z = {0u, 0u, 0u, 0u};
      B1[mb] = (g < 2) ? *(const u32x4*)(my + (16 * mb + c) * 32 + g * 16) : z;
    }

    // ---- Phase A: L1 nb=0,1 -> B2k0
    u32x4 B2k0[4], B2k1[4];
    {
      f32x4 a0[4], a1[4];
      bf16x8 A0 = *(const bf16x8*)(wbase + 0 * 1024);
      bf16x8 A1 = *(const bf16x8*)(wbase + 1 * 1024);
      f32x4 bv0 = *(const f32x4*)(b0 + i * 64 + 0 * 16 + g * 4);
      f32x4 bv1 = *(const f32x4*)(b0 + i * 64 + 1 * 16 + g * 4);
      #pragma unroll
      for (int mb = 0; mb < 4; ++mb)
        a0[mb] = __builtin_amdgcn_mfma_f32_16x16x32_bf16(
            A0, __builtin_bit_cast(bf16x8, B1[mb]), bv0, 0, 0, 0);
      #pragma unroll
      for (int mb = 0; mb < 4; ++mb)
        a1[mb] = __builtin_amdgcn_mfma_f32_16x16x32_bf16(
            A1, __builtin_bit_cast(bf16x8, B1[mb]), bv1, 0, 0, 0);
      #pragma unroll
      for (int mb = 0; mb < 4; ++mb) {
        unsigned p00 = cvt_pk_bf16(fmaxf(a0[mb][0], 0.f), fmaxf(a0[mb][1], 0.f));
        unsigned p01 = cvt_pk_bf16(fmaxf(a0[mb][2], 0.f), fmaxf(a0[mb][3], 0.f));
        unsigned p10 = cvt_pk_bf16(fmaxf(a1[mb][0], 0.f), fmaxf(a1[mb][1], 0.f));
        unsigned p11 = cvt_pk_bf16(fmaxf(a1[mb][2], 0.f), fmaxf(a1[mb][3], 0.f));
        B2k0[mb] = u32x4{p00, p01, p10, p11};
      }
    }
    // ---- Phase B: L1 nb=2,3 -> B2k1
    {
      f32x4 a0[4], a1[4];
      bf16x8 A0 = *(const bf16x8*)(wbase + 2 * 1024);
      bf16x8 A1 = *(const bf16x8*)(wbase + 3 * 1024);
      f32x4 bv0 = *(const f32x4*)(b0 + i * 64 + 2 * 16 + g * 4);
      f32x4 bv1 = *(const f32x4*)(b0 + i * 64 + 3 * 16 + g * 4);
      #pragma unroll
      for (int mb = 0; mb < 4; ++mb)
        a0[mb] = __builtin_amdgcn_mfma_f32_16x16x32_bf16(
            A0, __builtin_bit_cast(bf16x8, B1[mb]), bv0, 0, 0, 0);
      #pragma unroll
      for (int mb = 0; mb < 4; ++mb)
        a1[mb] = __builtin_amdgcn_mfma_f32_16x16x32_bf16(
            A1, __builtin_bit_cast(bf16x8, B1[mb]), bv1, 0, 0, 0);
      #pragma unroll
      for (int mb = 0; mb < 4; ++mb) {
        unsigned p00 = cvt_pk_bf16(fmaxf(a0[mb][0], 0.f), fmaxf(a0[mb][1], 0.f));
        unsigned p01 = cvt_pk_bf16(fmaxf(a0[mb][2], 0.f), fmaxf(a0[mb][3], 0.f));
        unsigned p10 = cvt_pk_bf16(fmaxf(a1[mb][0], 0.f), fmaxf(a1[mb][1], 0.f));
        unsigned p11 = cvt_pk_bf16(fmaxf(a1[mb][2], 0.f), fmaxf(a1[mb][3], 0.f));
        B2k1[mb] = u32x4{p00, p01, p10, p11};
      }
    }

    // ---- Phase C: L2 nb=0,1 -> B3k0
    u32x4 B3k0[4], B3k1[4];
    {
      f32x4 a0[4], a1[4];
      bf16x8 Ak0n0 = *(const bf16x8*)(wbase + (4 + 0 * 4 + 0) * 1024);
      bf16x8 Ak0n1 = *(const bf16x8*)(wbase + (4 + 0 * 4 + 1) * 1024);
      bf16x8 Ak1n0 = *(const bf16x8*)(wbase + (4 + 1 * 4 + 0) * 1024);
      bf16x8 Ak1n1 = *(const bf16x8*)(wbase + (4 + 1 * 4 + 1) * 1024);
      f32x4 bv0 = *(const f32x4*)(b1 + i * 64 + 0 * 16 + g * 4);
      f32x4 bv1 = *(const f32x4*)(b1 + i * 64 + 1 * 16 + g * 4);
      #pragma unroll
      for (int mb = 0; mb < 4; ++mb) {
        a0[mb] = __builtin_amdgcn_mfma_f32_16x16x32_bf16(
            Ak0n0, __builtin_bit_cast(bf16x8, B2k0[mb]), bv0, 0, 0, 0);
        a0[mb] = __builtin_amdgcn_mfma_f32_16x16x32_bf16(
            Ak1n0, __builtin_bit_cast(bf16x8, B2k1[mb]), a0[mb], 0, 0, 0);
      }
      #pragma unroll
      for (int mb = 0; mb < 4; ++mb) {
        a1[mb] = __builtin_amdgcn_mfma_f32_16x16x32_bf16(
            Ak0n1, __builtin_bit_cast(bf16x8, B2k0[mb]), bv1, 0, 0, 0);
        a1[mb] = __builtin_amdgcn_mfma_f32_16x16x32_bf16(
            Ak1n1, __builtin_bit_cast(bf16x8, B2k1[mb]), a1[mb], 0, 0, 0);
      }
      #pragma unroll
      for (int mb = 0; mb < 4; ++mb) {
        unsigned p00 = cvt_pk_bf16(fmaxf(a0[mb][0], 0.f), fmaxf(a0[mb][1], 0.f));
        unsigned p01 = cvt_pk_bf16(fmaxf(a0[mb][2], 0.f), fmaxf(a0[mb][3], 0.f));
        unsigned p10 = cvt_pk_bf16(fmaxf(a1[mb][0], 0.f), fmaxf(a1[mb][1], 0.f));
        unsigned p11 = cvt_pk_bf16(fmaxf(a1[mb][2], 0.f), fmaxf(a1[mb][3], 0.f));
        B3k0[mb] = u32x4{p00, p01, p10, p11};
      }
    }
    // ---- Phase D: L2 nb=2,3 -> B3k1
    {
      f32x4 a0[4], a1[4];
      bf16x8 Ak0n2 = *(const bf16x8*)(wbase + (4 + 0 * 4 + 2) * 1024);
      bf16x8 Ak0n3 = *(const bf16x8*)(wbase + (4 + 0 * 4 + 3) * 1024);
      bf16x8 Ak1n2 = *(const bf16x8*)(wbase + (4 + 1 * 4 + 2) * 1024);
      bf16x8 Ak1n3 = *(const bf16x8*)(wbase + (4 + 1 * 4 + 3) * 1024);
      f32x4 bv0 = *(const f32x4*)(b1 + i * 64 + 2 * 16 + g * 4);
      f32x4 bv1 = *(const f32x4*)(b1 + i * 64 + 3 * 16 + g * 4);
      #pragma unroll
      for (int mb = 0; mb < 4; ++mb) {
        a0[mb] = __builtin_amdgcn_mfma_f32_16x16x32_bf16(
            Ak0n2, __builtin_bit_cast(bf16x8, B2k0[mb]), bv0, 0, 0, 0);
        a0[mb] = __builtin_amdgcn_mfma_f32_16x16x32_bf16(
            Ak1n2, __builtin_bit_cast(bf16x8, B2k1[mb]), a0[mb], 0, 0, 0);
      }
      #pragma unroll
      for (int mb = 0; mb < 4; ++mb) {
        a1[mb] = __builtin_amdgcn_mfma_f32_16x16x32_bf16(
            Ak0n3, __builtin_bit_cast(bf16x8, B2k0[mb]), bv1, 0, 0, 0);
        a1[mb] = __builtin_amdgcn_mfma_f32_16x16x32_bf16(
            Ak1n3, __builtin_bit_cast(bf16x8, B2k1[mb]), a1[mb], 0, 0, 0);
      }
      #pragma unroll
      for (int mb = 0; mb < 4; ++mb) {
        unsigned p00 = cvt_pk_bf16(fmaxf(a0[mb][0], 0.f), fmaxf(a0[mb][1], 0.f));
        unsigned p01 = cvt_pk_bf16(fmaxf(a0[mb][2], 0.f), fmaxf(a0[mb][3], 0.f));
        unsigned p10 = cvt_pk_bf16(fmaxf(a1[mb][0], 0.f), fmaxf(a1[mb][1], 0.f));
        unsigned p11 = cvt_pk_bf16(fmaxf(a1[mb][2], 0.f), fmaxf(a1[mb][3], 0.f));
        B3k1[mb] = u32x4{p00, p01, p10, p11};
      }
    }

    // ---- Phase E: L3 chained
    f32x4 acc3[4];
    {
      bf16x8 A0 = *(const bf16x8*)(wbase + 12 * 1024);
      bf16x8 A1 = *(const bf16x8*)(wbase + 13 * 1024);
      f32x4 z = {0.f, 0.f, 0.f, 0.f};
      f32x4 bC2 = (g < 2) ? *(const f32x4*)(b2 + i * 8 + g * 4) : z;
      #pragma unroll
      for (int mb = 0; mb < 4; ++mb) {
        f32x4 tmp = __builtin_amdgcn_mfma_f32_16x16x32_bf16(
            A0, __builtin_bit_cast(bf16x8, B3k0[mb]), bC2, 0, 0, 0);
        acc3[mb] = __builtin_amdgcn_mfma_f32_16x16x32_bf16(
            A1, __builtin_bit_cast(bf16x8, B3k1[mb]), tmp, 0, 0, 0);
      }
    }

    // ---- O: wave-internal gather, then per-thread epilogue
    wfence();  // B1 reads (same region) complete
    if (g < 2) {
      #pragma unroll
      for (int mb = 0; mb < 4; ++mb)
        *(f32x4*)(my + (16 * mb + c) * 32 + g * 16) = acc3[mb];
    }
    wfence();
    {
      const float4 o0 = *(const float4*)(my + lane * 32);
      const float4 o1 = *(const float4*)(my + lane * 32 + 16);
      float sv0 = tanh_fast(o0.x), sv1 = tanh_fast(o0.y);
      float sv2 = tanh_fast(o0.z), sv3 = tanh_fast(o0.w);
      x[tr0 + 0] = x[tr0 + 0] * __expf(sv0) + o1.x;
      x[tr0 + 1] = x[tr0 + 1] * __expf(sv1) + o1.y;
      x[tr0 + 2] = x[tr0 + 2] * __expf(sv2) + o1.z;
      x[tr0 + 3] = x[tr0 + 3] * __expf(sv3) + o1.w;
      logdet += sv0 + sv1 + sv2 + sv3;
    }
  }

  float ss = 0.f;
  #pragma unroll
  for (int q = 0; q < 8; ++q) ss += x[q] * x[q];
  out[s] = -0.5f * ss - 7.3515082656373810f + logdet;
}

// ---------------------------------------------------------------------------
extern "C" void kernel_launch(void* const* d_in, const int* in_sizes, int n_in,
                              void* d_out, int out_size, void* d_ws, size_t ws_size,
                              hipStream_t stream) {
  const float* latent  = (const float*)d_in[0];
  const float* koopman = (const float*)d_in[1];
  const float* comm    = (const float*)d_in[2];
  const float* W0      = (const float*)d_in[3];
  const float* b0      = (const float*)d_in[4];
  const float* W1      = (const float*)d_in[5];
  const float* b1      = (const float*)d_in[6];
  const float* W2      = (const float*)d_in[7];
  const float* b2      = (const float*)d_in[8];
  float* out = (float*)d_out;

  float*    graphs_ws = (float*)d_ws;                        // 8 KB
  int*      cls_ws    = (int*)((char*)d_ws + 8192);          // 16 KB
  unsigned* wfrag_ws  = (unsigned*)((char*)d_ws + 24576);    // 42 KB

  // blocks: 0..31 eig | 32..47 argmax | 48..58 wpack
  prologue_kernel<<<59, 256, 0, stream>>>(
      koopman, comm, W0, W1, W2, graphs_ws, cls_ws, wfrag_ws);

  const int total = 32 * 4096 * 16;  // 2,097,152 samples
  causal_mfma_kernel<<<total / SPB, SPB, 0, stream>>>(
      latent, graphs_ws, cls_ws, wfrag_ws, b0, b1, b2, out);
}